// Round 1
// baseline (2848.778 us; speedup 1.0000x reference)
//
#include <hip/hip_runtime.h>
#include <math.h>

#define N_NODES 50000
#define N_EDGES 800000
#define NEG_SLOPE 0.2f

// ---------- helpers ----------
__device__ __forceinline__ float wred64(float v) {
#pragma unroll
    for (int off = 32; off > 0; off >>= 1) v += __shfl_xor(v, off, 64);
    return v;
}

// order-preserving fp32 <-> uint mapping for atomicMax
__device__ __forceinline__ unsigned enc_f32(float f) {
    unsigned u = __float_as_uint(f);
    return (u & 0x80000000u) ? ~u : (u | 0x80000000u);
}
__device__ __forceinline__ float dec_f32(unsigned e) {
    unsigned u = (e & 0x80000000u) ? (e & 0x7FFFFFFFu) : ~e;
    return __uint_as_float(u);
}

// ---------- tiny precompute: ve1[16][2], ve2[16] ----------
__global__ void k_ve(const float* __restrict__ We1, const float* __restrict__ atte1,
                     const float* __restrict__ We2, const float* __restrict__ atte2,
                     float* __restrict__ ve1, float* __restrict__ ve2) {
    int t = threadIdx.x;
    if (t < 32) {
        int k = t >> 1, h = t & 1;
        float s = 0.f;
        for (int c = 0; c < 64; ++c) s = fmaf(We1[k * 128 + h * 64 + c], atte1[h * 64 + c], s);
        ve1[k * 2 + h] = s;
    } else if (t < 48) {
        int k = t - 32;
        float s = 0.f;
        for (int c = 0; c < 64; ++c) s = fmaf(We2[k * 64 + c], atte2[c], s);
        ve2[k] = s;
    }
}

// ---------- conv1 node transform: h1 = x @ W1 (128->128), a_s1/a_d1 ----------
__global__ __launch_bounds__(128) void k_gemm1(const float* __restrict__ x, const float* __restrict__ W1,
                                               const float* __restrict__ atts, const float* __restrict__ attd,
                                               float* __restrict__ h1, float* __restrict__ a_s,
                                               float* __restrict__ a_d) {
    __shared__ float xs[128];
    int n = blockIdx.x;
    int j = threadIdx.x;
    xs[j] = x[n * 128 + j];
    __syncthreads();
    float acc = 0.f;
#pragma unroll 8
    for (int k = 0; k < 128; ++k) acc = fmaf(xs[k], W1[k * 128 + j], acc);
    h1[n * 128 + j] = acc;
    float ps = wred64(acc * atts[j]);
    float pd = wred64(acc * attd[j]);
    if ((j & 63) == 0) {
        int head = j >> 6;
        a_s[n * 2 + head] = ps;
        a_d[n * 2 + head] = pd;
    }
}

// ---------- edge attention contributions: a_e1[E,2], a_e2[E] ----------
__global__ void k_ae(const float* __restrict__ ea, const float* __restrict__ ve1,
                     const float* __restrict__ ve2, float* __restrict__ ae1, float* __restrict__ ae2) {
    int e = blockIdx.x * blockDim.x + threadIdx.x;
    if (e >= N_EDGES) return;
    float s0 = 0.f, s1 = 0.f, s2 = 0.f;
#pragma unroll
    for (int k = 0; k < 16; ++k) {
        float v = ea[e * 16 + k];
        s0 = fmaf(v, ve1[k * 2 + 0], s0);
        s1 = fmaf(v, ve1[k * 2 + 1], s1);
        s2 = fmaf(v, ve2[k], s2);
    }
    ae1[e * 2 + 0] = s0;
    ae1[e * 2 + 1] = s1;
    ae2[e] = s2;
}

// ---------- logits + segment max ----------
template <int H>
__global__ void k_logitmax(const int* __restrict__ src, const int* __restrict__ dst,
                           const float* __restrict__ a_s, const float* __restrict__ a_d,
                           const float* __restrict__ a_e, float* __restrict__ logits,
                           unsigned* __restrict__ menc) {
    int e = blockIdx.x * blockDim.x + threadIdx.x;
    if (e >= N_EDGES) return;
    int s = src[e], d = dst[e];
#pragma unroll
    for (int h = 0; h < H; ++h) {
        float z = a_s[s * H + h] + a_d[d * H + h] + a_e[e * H + h];
        z = z > 0.f ? z : NEG_SLOPE * z;
        logits[e * H + h] = z;
        atomicMax(&menc[d * H + h], enc_f32(z));
    }
}

// ---------- exp + segment sum (in-place logits -> ex) ----------
template <int H>
__global__ void k_expsum(const int* __restrict__ dst, const unsigned* __restrict__ menc,
                         float* __restrict__ lex, float* __restrict__ denom) {
    int e = blockIdx.x * blockDim.x + threadIdx.x;
    if (e >= N_EDGES) return;
    int d = dst[e];
#pragma unroll
    for (int h = 0; h < H; ++h) {
        float m = dec_f32(menc[d * H + h]);
        float ex = __expf(lex[e * H + h] - m);
        lex[e * H + h] = ex;
        atomicAdd(&denom[d * H + h], ex);
    }
}

// ---------- weighted message scatter: out[dst] += h[src] * alpha ----------
template <int C, int H>
__global__ void k_scatter(const int* __restrict__ src, const int* __restrict__ dst,
                          const float* __restrict__ hfeat, const float* __restrict__ lex,
                          const float* __restrict__ denom, float* __restrict__ outacc) {
    constexpr int L = C / 4;
    int gid = blockIdx.x * blockDim.x + threadIdx.x;
    int e = gid / L;
    int l = gid % L;
    if (e >= N_EDGES) return;
    int s = src[e], d = dst[e];
    int h = (4 * l) >> 6;  // head for this 4-channel chunk (0 when C=64)
    float alpha = lex[e * H + h] / (denom[d * H + h] + 1e-16f);
    const float4 v = *reinterpret_cast<const float4*>(&hfeat[s * C + 4 * l]);
    float* o = &outacc[d * C + 4 * l];
    atomicAdd(o + 0, v.x * alpha);
    atomicAdd(o + 1, v.y * alpha);
    atomicAdd(o + 2, v.z * alpha);
    atomicAdd(o + 3, v.w * alpha);
}

// ---------- bias + ELU (in-place ok) ----------
__global__ void k_bias_elu(const float* __restrict__ in, const float* __restrict__ b,
                           float* __restrict__ out, int n, int cmask) {
    int i = blockIdx.x * blockDim.x + threadIdx.x;
    if (i >= n) return;
    float v = in[i] + b[i & cmask];
    out[i] = v > 0.f ? v : expm1f(v);
}

// ---------- conv2 node transform: h2 = h2in @ W2 (128->64), a_s2/a_d2 ----------
__global__ __launch_bounds__(64) void k_gemm2(const float* __restrict__ xin, const float* __restrict__ W,
                                              const float* __restrict__ atts, const float* __restrict__ attd,
                                              float* __restrict__ h2, float* __restrict__ a_s,
                                              float* __restrict__ a_d) {
    __shared__ float xs[128];
    int n = blockIdx.x;
    int j = threadIdx.x;
    xs[j] = xin[n * 128 + j];
    xs[j + 64] = xin[n * 128 + 64 + j];
    __syncthreads();
    float acc = 0.f;
#pragma unroll 8
    for (int k = 0; k < 128; ++k) acc = fmaf(xs[k], W[k * 64 + j], acc);
    h2[n * 64 + j] = acc;
    float ps = wred64(acc * atts[j]);
    float pd = wred64(acc * attd[j]);
    if (j == 0) {
        a_s[n] = ps;
        a_d[n] = pd;
    }
}

// ---------- classifier node-side: P1 = hf@Wc1[0:64]+bc1, P2 = hf@Wc1[64:128] ----------
__global__ __launch_bounds__(64) void k_p12(const float* __restrict__ hf, const float* __restrict__ Wc1,
                                            const float* __restrict__ bc1, float* __restrict__ P1,
                                            float* __restrict__ P2) {
    __shared__ float xs[64];
    int n = blockIdx.x, j = threadIdx.x;
    xs[j] = hf[n * 64 + j];
    __syncthreads();
    float a1 = bc1[j], a2 = 0.f;
#pragma unroll 8
    for (int k = 0; k < 64; ++k) {
        a1 = fmaf(xs[k], Wc1[k * 64 + j], a1);
        a2 = fmaf(xs[k], Wc1[(64 + k) * 64 + j], a2);
    }
    P1[n * 64 + j] = a1;
    P2[n * 64 + j] = a2;
}

// ---------- classifier edge-side: out[e] = relu(P1[s]+P2[d]+ea@Wc1c) . Wc2 + bc2 ----------
__global__ __launch_bounds__(256) void k_final(const int* __restrict__ src, const int* __restrict__ dst,
                                               const float* __restrict__ ea, const float* __restrict__ P1,
                                               const float* __restrict__ P2, const float* __restrict__ Wc1,
                                               const float* __restrict__ Wc2, const float* __restrict__ bc2,
                                               float* __restrict__ out) {
    __shared__ float wc1c[16 * 64];
    __shared__ float wc2s[64];
    int tid = threadIdx.x;
    for (int i = tid; i < 16 * 64; i += 256) wc1c[i] = Wc1[128 * 64 + i];
    if (tid < 64) wc2s[tid] = Wc2[tid];
    __syncthreads();
    int wid = tid >> 6, lane = tid & 63;
    int e = blockIdx.x * 4 + wid;
    if (e >= N_EDGES) return;
    int s = src[e], d = dst[e];
    float hid = P1[s * 64 + lane] + P2[d * 64 + lane];
#pragma unroll
    for (int k = 0; k < 16; ++k) hid = fmaf(ea[e * 16 + k], wc1c[k * 64 + lane], hid);
    hid = fmaxf(hid, 0.f);
    float v = wred64(hid * wc2s[lane]);
    if (lane == 0) out[e] = v + bc2[0];
}

extern "C" void kernel_launch(void* const* d_in, const int* in_sizes, int n_in,
                              void* d_out, int out_size, void* d_ws, size_t ws_size,
                              hipStream_t stream) {
    const float* x     = (const float*)d_in[0];
    const int*   eidx  = (const int*)d_in[1];
    const float* ea    = (const float*)d_in[2];
    const float* W1    = (const float*)d_in[3];
    const float* atts1 = (const float*)d_in[4];
    const float* attd1 = (const float*)d_in[5];
    const float* We1   = (const float*)d_in[6];
    const float* atte1 = (const float*)d_in[7];
    const float* b1    = (const float*)d_in[8];
    const float* W2    = (const float*)d_in[9];
    const float* atts2 = (const float*)d_in[10];
    const float* attd2 = (const float*)d_in[11];
    const float* We2   = (const float*)d_in[12];
    const float* atte2 = (const float*)d_in[13];
    const float* b2    = (const float*)d_in[14];
    const float* Wc1   = (const float*)d_in[15];
    const float* bc1   = (const float*)d_in[16];
    const float* Wc2   = (const float*)d_in[17];
    const float* bc2   = (const float*)d_in[18];
    const int* srcp = eidx;
    const int* dstp = eidx + N_EDGES;
    float* out = (float*)d_out;

    char* w = (char*)d_ws;
    size_t off = 0;
    auto alloc = [&](size_t bytes) -> void* {
        void* p = w + off;
        off += (bytes + 255) & ~size_t(255);
        return p;
    };

    // persistent-ish scratch (aliased where lifetimes permit)
    float* h1   = (float*)alloc(N_NODES * 128 * sizeof(float));  // conv1 features; later reused as P1/P2
    float* as1  = (float*)alloc(N_NODES * 2 * sizeof(float));
    float* ad1  = (float*)alloc(N_NODES * 2 * sizeof(float));
    float* ae1  = (float*)alloc(N_EDGES * 2 * sizeof(float));    // with lex1 reused as h2 later
    float* lex1 = (float*)alloc(N_EDGES * 2 * sizeof(float));
    float* as2  = (float*)alloc(N_NODES * sizeof(float));
    float* ad2  = (float*)alloc(N_NODES * sizeof(float));
    float* ae2  = (float*)alloc(N_EDGES * sizeof(float));
    float* lex2 = (float*)alloc(N_EDGES * sizeof(float));
    float* ve1  = (float*)alloc(32 * sizeof(float));
    float* ve2  = (float*)alloc(16 * sizeof(float));

    // aliases (lifetime-disjoint)
    float* h2 = ae1;            // [N,64]: written after ae1/lex1 are dead
    float* P1 = h1;             // [N,64]: written after h1 is dead
    float* P2 = h1 + N_NODES * 64;

    // zeroed-every-call region
    char* zstart = w + off;
    unsigned* m1  = (unsigned*)alloc(N_NODES * 2 * sizeof(unsigned));
    float* den1   = (float*)alloc(N_NODES * 2 * sizeof(float));
    float* out1   = (float*)alloc(N_NODES * 128 * sizeof(float));
    unsigned* m2  = (unsigned*)alloc(N_NODES * sizeof(unsigned));
    float* den2   = (float*)alloc(N_NODES * sizeof(float));
    float* out2   = (float*)alloc(N_NODES * 64 * sizeof(float));
    size_t zbytes = (size_t)((w + off) - zstart);
    hipMemsetAsync(zstart, 0, zbytes, stream);

    const int EB = (N_EDGES + 255) / 256;  // 3125

    k_ve<<<1, 64, 0, stream>>>(We1, atte1, We2, atte2, ve1, ve2);
    k_gemm1<<<N_NODES, 128, 0, stream>>>(x, W1, atts1, attd1, h1, as1, ad1);
    k_ae<<<EB, 256, 0, stream>>>(ea, ve1, ve2, ae1, ae2);

    // conv1 attention + aggregate
    k_logitmax<2><<<EB, 256, 0, stream>>>(srcp, dstp, as1, ad1, ae1, lex1, m1);
    k_expsum<2><<<EB, 256, 0, stream>>>(dstp, m1, lex1, den1);
    k_scatter<128, 2><<<(N_EDGES * 32) / 256, 256, 0, stream>>>(srcp, dstp, h1, lex1, den1, out1);
    k_bias_elu<<<(N_NODES * 128 + 255) / 256, 256, 0, stream>>>(out1, b1, out1, N_NODES * 128, 127);

    // conv2
    k_gemm2<<<N_NODES, 64, 0, stream>>>(out1, W2, atts2, attd2, h2, as2, ad2);
    k_logitmax<1><<<EB, 256, 0, stream>>>(srcp, dstp, as2, ad2, ae2, lex2, m2);
    k_expsum<1><<<EB, 256, 0, stream>>>(dstp, m2, lex2, den2);
    k_scatter<64, 1><<<(N_EDGES * 16) / 256, 256, 0, stream>>>(srcp, dstp, h2, lex2, den2, out2);
    k_bias_elu<<<(N_NODES * 64 + 255) / 256, 256, 0, stream>>>(out2, b2, out2, N_NODES * 64, 63);

    // edge classifier
    k_p12<<<N_NODES, 64, 0, stream>>>(out2, Wc1, bc1, P1, P2);
    k_final<<<N_EDGES / 4, 256, 0, stream>>>(srcp, dstp, ea, P1, P2, Wc1, Wc2, bc2, out);
}

// Round 2
// 1128.459 us; speedup vs baseline: 2.5245x; 2.5245x over previous
//
#include <hip/hip_runtime.h>
#include <math.h>

#define N_NODES 50000
#define N_EDGES 800000
#define NEG_SLOPE 0.2f

// ---------- helpers ----------
__device__ __forceinline__ float wred64(float v) {
#pragma unroll
    for (int off = 32; off > 0; off >>= 1) v += __shfl_xor(v, off, 64);
    return v;
}

// order-preserving fp32 <-> uint mapping for atomicMax
__device__ __forceinline__ unsigned enc_f32(float f) {
    unsigned u = __float_as_uint(f);
    return (u & 0x80000000u) ? ~u : (u | 0x80000000u);
}
__device__ __forceinline__ float dec_f32(unsigned e) {
    unsigned u = (e & 0x80000000u) ? (e & 0x7FFFFFFFu) : ~e;
    return __uint_as_float(u);
}

// ---------- tiny precompute: ve1[16][2], ve2[16] ----------
__global__ void k_ve(const float* __restrict__ We1, const float* __restrict__ atte1,
                     const float* __restrict__ We2, const float* __restrict__ atte2,
                     float* __restrict__ ve1, float* __restrict__ ve2) {
    int t = threadIdx.x;
    if (t < 32) {
        int k = t >> 1, h = t & 1;
        float s = 0.f;
        for (int c = 0; c < 64; ++c) s = fmaf(We1[k * 128 + h * 64 + c], atte1[h * 64 + c], s);
        ve1[k * 2 + h] = s;
    } else if (t < 48) {
        int k = t - 32;
        float s = 0.f;
        for (int c = 0; c < 64; ++c) s = fmaf(We2[k * 64 + c], atte2[c], s);
        ve2[k] = s;
    }
}

// ---------- conv1 node transform: h1 = x @ W1 (128->128), a_s1/a_d1 ----------
__global__ __launch_bounds__(128) void k_gemm1(const float* __restrict__ x, const float* __restrict__ W1,
                                               const float* __restrict__ atts, const float* __restrict__ attd,
                                               float* __restrict__ h1, float* __restrict__ a_s,
                                               float* __restrict__ a_d) {
    __shared__ float xs[128];
    int n = blockIdx.x;
    int j = threadIdx.x;
    xs[j] = x[n * 128 + j];
    __syncthreads();
    float acc = 0.f;
#pragma unroll 8
    for (int k = 0; k < 128; ++k) acc = fmaf(xs[k], W1[k * 128 + j], acc);
    h1[n * 128 + j] = acc;
    float ps = wred64(acc * atts[j]);
    float pd = wred64(acc * attd[j]);
    if ((j & 63) == 0) {
        int head = j >> 6;
        a_s[n * 2 + head] = ps;
        a_d[n * 2 + head] = pd;
    }
}

// ---------- edge attention contributions: a_e1[E,2], a_e2[E] ----------
__global__ void k_ae(const float* __restrict__ ea, const float* __restrict__ ve1,
                     const float* __restrict__ ve2, float* __restrict__ ae1, float* __restrict__ ae2) {
    int e = blockIdx.x * blockDim.x + threadIdx.x;
    if (e >= N_EDGES) return;
    float s0 = 0.f, s1 = 0.f, s2 = 0.f;
#pragma unroll
    for (int k = 0; k < 16; ++k) {
        float v = ea[e * 16 + k];
        s0 = fmaf(v, ve1[k * 2 + 0], s0);
        s1 = fmaf(v, ve1[k * 2 + 1], s1);
        s2 = fmaf(v, ve2[k], s2);
    }
    ae1[e * 2 + 0] = s0;
    ae1[e * 2 + 1] = s1;
    ae2[e] = s2;
}

// ---------- CSR build: histogram, scan, fill ----------
__global__ void k_hist(const int* __restrict__ dst, int* __restrict__ cnt) {
    int e = blockIdx.x * blockDim.x + threadIdx.x;
    if (e < N_EDGES) atomicAdd(&cnt[dst[e]], 1);
}

__global__ __launch_bounds__(1024) void k_scan(const int* __restrict__ cnt, int* __restrict__ rp,
                                               int* __restrict__ cursor) {
    __shared__ int part[1024];
    int t = threadIdx.x;
    const int CH = (N_NODES + 1023) / 1024;  // 49
    int base = t * CH;
    int s = 0;
    for (int i = 0; i < CH; ++i) {
        int idx = base + i;
        if (idx < N_NODES) s += cnt[idx];
    }
    part[t] = s;
    __syncthreads();
    for (int off = 1; off < 1024; off <<= 1) {
        int v = (t >= off) ? part[t - off] : 0;
        __syncthreads();
        part[t] += v;
        __syncthreads();
    }
    int run = (t > 0) ? part[t - 1] : 0;
    for (int i = 0; i < CH; ++i) {
        int idx = base + i;
        if (idx < N_NODES) {
            rp[idx] = run;
            cursor[idx] = run;
            run += cnt[idx];
        }
    }
    if (t == 1023) rp[N_NODES] = part[1023];
}

__global__ void k_fill(const int* __restrict__ dst, int* __restrict__ cursor, int* __restrict__ eord) {
    int e = blockIdx.x * blockDim.x + threadIdx.x;
    if (e < N_EDGES) {
        int p = atomicAdd(&cursor[dst[e]], 1);
        eord[p] = e;
    }
}

// ---------- logits + segment max ----------
template <int H>
__global__ void k_logitmax(const int* __restrict__ src, const int* __restrict__ dst,
                           const float* __restrict__ a_s, const float* __restrict__ a_d,
                           const float* __restrict__ a_e, float* __restrict__ logits,
                           unsigned* __restrict__ menc) {
    int e = blockIdx.x * blockDim.x + threadIdx.x;
    if (e >= N_EDGES) return;
    int s = src[e], d = dst[e];
#pragma unroll
    for (int h = 0; h < H; ++h) {
        float z = a_s[s * H + h] + a_d[d * H + h] + a_e[e * H + h];
        z = z > 0.f ? z : NEG_SLOPE * z;
        logits[e * H + h] = z;
        atomicMax(&menc[d * H + h], enc_f32(z));
    }
}

// ---------- exp + segment sum (in-place logits -> ex) ----------
template <int H>
__global__ void k_expsum(const int* __restrict__ dst, const unsigned* __restrict__ menc,
                         float* __restrict__ lex, float* __restrict__ denom) {
    int e = blockIdx.x * blockDim.x + threadIdx.x;
    if (e >= N_EDGES) return;
    int d = dst[e];
#pragma unroll
    for (int h = 0; h < H; ++h) {
        float m = dec_f32(menc[d * H + h]);
        float ex = __expf(lex[e * H + h] - m);
        lex[e * H + h] = ex;
        atomicAdd(&denom[d * H + h], ex);
    }
}

// ---------- per-dst gather aggregation + bias + ELU ----------
template <int C, int H>
__global__ __launch_bounds__(C) void k_gather(const int* __restrict__ rp, const int* __restrict__ eord,
                                              const int* __restrict__ src, const float* __restrict__ hfeat,
                                              const float* __restrict__ lex, const float* __restrict__ den,
                                              const float* __restrict__ bias, float* __restrict__ outp) {
    int n = blockIdx.x;
    int j = threadIdx.x;
    int beg = rp[n], end = rp[n + 1];
    __shared__ int es[C];
    __shared__ float al[C * H];
    float dinv[H];
#pragma unroll
    for (int h = 0; h < H; ++h) dinv[h] = 1.f / (den[n * H + h] + 1e-16f);
    float acc = 0.f;
    const int hsel = (H == 2) ? (j >> 6) : 0;
    for (int base = beg; base < end; base += C) {
        int cnt = min(C, end - base);
        __syncthreads();
        if (j < cnt) {
            int e = eord[base + j];
            es[j] = src[e];
#pragma unroll
            for (int h = 0; h < H; ++h) al[j * H + h] = lex[e * H + h] * dinv[h];
        }
        __syncthreads();
#pragma unroll 4
        for (int i = 0; i < cnt; ++i) {
            int s = es[i];
            acc = fmaf(hfeat[s * C + j], al[i * H + hsel], acc);
        }
    }
    float v = acc + bias[j];
    outp[n * C + j] = v > 0.f ? v : expm1f(v);
}

// ---------- conv2 node transform: h2 = h2in @ W2 (128->64), a_s2/a_d2 ----------
__global__ __launch_bounds__(64) void k_gemm2(const float* __restrict__ xin, const float* __restrict__ W,
                                              const float* __restrict__ atts, const float* __restrict__ attd,
                                              float* __restrict__ h2, float* __restrict__ a_s,
                                              float* __restrict__ a_d) {
    __shared__ float xs[128];
    int n = blockIdx.x;
    int j = threadIdx.x;
    xs[j] = xin[n * 128 + j];
    xs[j + 64] = xin[n * 128 + 64 + j];
    __syncthreads();
    float acc = 0.f;
#pragma unroll 8
    for (int k = 0; k < 128; ++k) acc = fmaf(xs[k], W[k * 64 + j], acc);
    h2[n * 64 + j] = acc;
    float ps = wred64(acc * atts[j]);
    float pd = wred64(acc * attd[j]);
    if (j == 0) {
        a_s[n] = ps;
        a_d[n] = pd;
    }
}

// ---------- classifier node-side: P1 = hf@Wc1[0:64]+bc1, P2 = hf@Wc1[64:128] ----------
__global__ __launch_bounds__(64) void k_p12(const float* __restrict__ hf, const float* __restrict__ Wc1,
                                            const float* __restrict__ bc1, float* __restrict__ P1,
                                            float* __restrict__ P2) {
    __shared__ float xs[64];
    int n = blockIdx.x, j = threadIdx.x;
    xs[j] = hf[n * 64 + j];
    __syncthreads();
    float a1 = bc1[j], a2 = 0.f;
#pragma unroll 8
    for (int k = 0; k < 64; ++k) {
        a1 = fmaf(xs[k], Wc1[k * 64 + j], a1);
        a2 = fmaf(xs[k], Wc1[(64 + k) * 64 + j], a2);
    }
    P1[n * 64 + j] = a1;
    P2[n * 64 + j] = a2;
}

// ---------- classifier edge-side: out[e] = relu(P1[s]+P2[d]+ea@Wc1c) . Wc2 + bc2 ----------
__global__ __launch_bounds__(256) void k_final(const int* __restrict__ src, const int* __restrict__ dst,
                                               const float* __restrict__ ea, const float* __restrict__ P1,
                                               const float* __restrict__ P2, const float* __restrict__ Wc1,
                                               const float* __restrict__ Wc2, const float* __restrict__ bc2,
                                               float* __restrict__ out) {
    __shared__ float wc1c[16 * 64];
    __shared__ float wc2s[64];
    int tid = threadIdx.x;
    for (int i = tid; i < 16 * 64; i += 256) wc1c[i] = Wc1[128 * 64 + i];
    if (tid < 64) wc2s[tid] = Wc2[tid];
    __syncthreads();
    int wid = tid >> 6, lane = tid & 63;
    int e = blockIdx.x * 4 + wid;
    if (e >= N_EDGES) return;
    int s = src[e], d = dst[e];
    float hid = P1[s * 64 + lane] + P2[d * 64 + lane];
#pragma unroll
    for (int k = 0; k < 16; ++k) hid = fmaf(ea[e * 16 + k], wc1c[k * 64 + lane], hid);
    hid = fmaxf(hid, 0.f);
    float v = wred64(hid * wc2s[lane]);
    if (lane == 0) out[e] = v + bc2[0];
}

extern "C" void kernel_launch(void* const* d_in, const int* in_sizes, int n_in,
                              void* d_out, int out_size, void* d_ws, size_t ws_size,
                              hipStream_t stream) {
    const float* x     = (const float*)d_in[0];
    const int*   eidx  = (const int*)d_in[1];
    const float* ea    = (const float*)d_in[2];
    const float* W1    = (const float*)d_in[3];
    const float* atts1 = (const float*)d_in[4];
    const float* attd1 = (const float*)d_in[5];
    const float* We1   = (const float*)d_in[6];
    const float* atte1 = (const float*)d_in[7];
    const float* b1    = (const float*)d_in[8];
    const float* W2    = (const float*)d_in[9];
    const float* atts2 = (const float*)d_in[10];
    const float* attd2 = (const float*)d_in[11];
    const float* We2   = (const float*)d_in[12];
    const float* atte2 = (const float*)d_in[13];
    const float* b2    = (const float*)d_in[14];
    const float* Wc1   = (const float*)d_in[15];
    const float* bc1   = (const float*)d_in[16];
    const float* Wc2   = (const float*)d_in[17];
    const float* bc2   = (const float*)d_in[18];
    const int* srcp = eidx;
    const int* dstp = eidx + N_EDGES;
    float* out = (float*)d_out;

    char* w = (char*)d_ws;
    size_t off = 0;
    auto alloc = [&](size_t bytes) -> void* {
        void* p = w + off;
        off += (bytes + 255) & ~size_t(255);
        return p;
    };

    // persistent scratch (aliased where lifetimes permit)
    float* h1   = (float*)alloc(N_NODES * 128 * sizeof(float));  // conv1 features; later reused as P1/P2
    float* as1  = (float*)alloc(N_NODES * 2 * sizeof(float));
    float* ad1  = (float*)alloc(N_NODES * 2 * sizeof(float));
    float* ae1  = (float*)alloc(N_EDGES * 2 * sizeof(float));    // with lex1 reused as h2 later
    float* lex1 = (float*)alloc(N_EDGES * 2 * sizeof(float));
    float* as2  = (float*)alloc(N_NODES * sizeof(float));
    float* ad2  = (float*)alloc(N_NODES * sizeof(float));
    float* ae2  = (float*)alloc(N_EDGES * sizeof(float));
    float* lex2 = (float*)alloc(N_EDGES * sizeof(float));
    float* ve1  = (float*)alloc(32 * sizeof(float));
    float* ve2  = (float*)alloc(16 * sizeof(float));
    int*   rp     = (int*)alloc((N_NODES + 1) * sizeof(int));
    int*   eord   = (int*)alloc(N_EDGES * sizeof(int));
    int*   cursor = (int*)alloc(N_NODES * sizeof(int));
    float* out1   = (float*)alloc(N_NODES * 128 * sizeof(float));
    float* out2   = (float*)alloc(N_NODES * 64 * sizeof(float));

    // aliases (lifetime-disjoint)
    float* h2 = ae1;            // [N,64] overlaps ae1+lex1, both dead by then
    float* P1 = h1;             // [N,64]: written after h1 is dead
    float* P2 = h1 + N_NODES * 64;

    // zeroed-every-call region
    char* zstart = w + off;
    unsigned* m1  = (unsigned*)alloc(N_NODES * 2 * sizeof(unsigned));
    float* den1   = (float*)alloc(N_NODES * 2 * sizeof(float));
    unsigned* m2  = (unsigned*)alloc(N_NODES * sizeof(unsigned));
    float* den2   = (float*)alloc(N_NODES * sizeof(float));
    int*   cnt    = (int*)alloc(N_NODES * sizeof(int));
    size_t zbytes = (size_t)((w + off) - zstart);
    hipMemsetAsync(zstart, 0, zbytes, stream);

    const int EB = (N_EDGES + 255) / 256;  // 3125

    // CSR build (shared by both conv layers)
    k_hist<<<EB, 256, 0, stream>>>(dstp, cnt);
    k_scan<<<1, 1024, 0, stream>>>(cnt, rp, cursor);
    k_fill<<<EB, 256, 0, stream>>>(dstp, cursor, eord);

    k_ve<<<1, 64, 0, stream>>>(We1, atte1, We2, atte2, ve1, ve2);
    k_gemm1<<<N_NODES, 128, 0, stream>>>(x, W1, atts1, attd1, h1, as1, ad1);
    k_ae<<<EB, 256, 0, stream>>>(ea, ve1, ve2, ae1, ae2);

    // conv1 attention + aggregate
    k_logitmax<2><<<EB, 256, 0, stream>>>(srcp, dstp, as1, ad1, ae1, lex1, m1);
    k_expsum<2><<<EB, 256, 0, stream>>>(dstp, m1, lex1, den1);
    k_gather<128, 2><<<N_NODES, 128, 0, stream>>>(rp, eord, srcp, h1, lex1, den1, b1, out1);

    // conv2
    k_gemm2<<<N_NODES, 64, 0, stream>>>(out1, W2, atts2, attd2, h2, as2, ad2);
    k_logitmax<1><<<EB, 256, 0, stream>>>(srcp, dstp, as2, ad2, ae2, lex2, m2);
    k_expsum<1><<<EB, 256, 0, stream>>>(dstp, m2, lex2, den2);
    k_gather<64, 1><<<N_NODES, 64, 0, stream>>>(rp, eord, srcp, h2, lex2, den2, b2, out2);

    // edge classifier
    k_p12<<<N_NODES, 64, 0, stream>>>(out2, Wc1, bc1, P1, P2);
    k_final<<<N_EDGES / 4, 256, 0, stream>>>(srcp, dstp, ea, P1, P2, Wc1, Wc2, bc2, out);
}

// Round 3
// 836.196 us; speedup vs baseline: 3.4068x; 1.3495x over previous
//
#include <hip/hip_runtime.h>
#include <math.h>

#define N_NODES 50000
#define N_EDGES 800000
#define NEG_SLOPE 0.2f

// ---------- helpers ----------
__device__ __forceinline__ float wred64(float v) {
#pragma unroll
    for (int off = 32; off > 0; off >>= 1) v += __shfl_xor(v, off, 64);
    return v;
}
__device__ __forceinline__ float wmax64(float v) {
#pragma unroll
    for (int off = 32; off > 0; off >>= 1) v = fmaxf(v, __shfl_xor(v, off, 64));
    return v;
}

// ---------- tiny precompute: ve1[16][2], ve2[16] ----------
__global__ void k_ve(const float* __restrict__ We1, const float* __restrict__ atte1,
                     const float* __restrict__ We2, const float* __restrict__ atte2,
                     float* __restrict__ ve1, float* __restrict__ ve2) {
    int t = threadIdx.x;
    if (t < 32) {
        int k = t >> 1, h = t & 1;
        float s = 0.f;
        for (int c = 0; c < 64; ++c) s = fmaf(We1[k * 128 + h * 64 + c], atte1[h * 64 + c], s);
        ve1[k * 2 + h] = s;
    } else if (t < 48) {
        int k = t - 32;
        float s = 0.f;
        for (int c = 0; c < 64; ++c) s = fmaf(We2[k * 64 + c], atte2[c], s);
        ve2[k] = s;
    }
}

// ---------- conv1 node transform: h1 = x @ W1 (128->128), a_s1/a_d1 ----------
// W column cached in 128 VGPRs; 40 nodes per block; x rows are wave-uniform -> scalar loads.
#define G1 40
__global__ __launch_bounds__(128) void k_gemm1(const float* __restrict__ x, const float* __restrict__ W1,
                                               const float* __restrict__ atts, const float* __restrict__ attd,
                                               float* __restrict__ h1, float* __restrict__ a_s,
                                               float* __restrict__ a_d) {
    int j = threadIdx.x;
    int head = j >> 6;
    float wr[128];
#pragma unroll
    for (int k = 0; k < 128; ++k) wr[k] = W1[k * 128 + j];
    float asj = atts[j], adj = attd[j];
    int n0 = blockIdx.x * G1;
    for (int n = n0; n < n0 + G1; n += 2) {
        const float* xr0 = x + (size_t)n * 128;
        const float* xr1 = xr0 + 128;
        float a0 = 0.f, a1 = 0.f;
#pragma unroll
        for (int k = 0; k < 128; ++k) {
            a0 = fmaf(xr0[k], wr[k], a0);
            a1 = fmaf(xr1[k], wr[k], a1);
        }
        h1[(size_t)n * 128 + j] = a0;
        h1[(size_t)(n + 1) * 128 + j] = a1;
        float ps0 = wred64(a0 * asj), pd0 = wred64(a0 * adj);
        float ps1 = wred64(a1 * asj), pd1 = wred64(a1 * adj);
        if ((j & 63) == 0) {
            a_s[n * 2 + head] = ps0;
            a_d[n * 2 + head] = pd0;
            a_s[(n + 1) * 2 + head] = ps1;
            a_d[(n + 1) * 2 + head] = pd1;
        }
    }
}

// ---------- conv2 node transform: h2 = h2in @ W2 (128->64), a_s2/a_d2 ----------
#define G2 40
__global__ __launch_bounds__(64) void k_gemm2(const float* __restrict__ xin, const float* __restrict__ W,
                                              const float* __restrict__ atts, const float* __restrict__ attd,
                                              float* __restrict__ h2, float* __restrict__ a_s,
                                              float* __restrict__ a_d) {
    int j = threadIdx.x;
    float wr[128];
#pragma unroll
    for (int k = 0; k < 128; ++k) wr[k] = W[k * 64 + j];
    float asj = atts[j], adj = attd[j];
    int n0 = blockIdx.x * G2;
    for (int n = n0; n < n0 + G2; n += 2) {
        const float* xr0 = xin + (size_t)n * 128;
        const float* xr1 = xr0 + 128;
        float a0 = 0.f, a1 = 0.f;
#pragma unroll
        for (int k = 0; k < 128; ++k) {
            a0 = fmaf(xr0[k], wr[k], a0);
            a1 = fmaf(xr1[k], wr[k], a1);
        }
        h2[(size_t)n * 64 + j] = a0;
        h2[(size_t)(n + 1) * 64 + j] = a1;
        float ps0 = wred64(a0 * asj), pd0 = wred64(a0 * adj);
        float ps1 = wred64(a1 * asj), pd1 = wred64(a1 * adj);
        if (j == 0) {
            a_s[n] = ps0;
            a_d[n] = pd0;
            a_s[n + 1] = ps1;
            a_d[n + 1] = pd1;
        }
    }
}

// ---------- classifier node-side: P1 = hf@Wc1[0:64]+bc1, P2 = hf@Wc1[64:128] ----------
__global__ __launch_bounds__(64) void k_p12(const float* __restrict__ hf, const float* __restrict__ Wc1,
                                            const float* __restrict__ bc1, float* __restrict__ P1,
                                            float* __restrict__ P2) {
    int j = threadIdx.x;
    float wr1[64], wr2[64];
#pragma unroll
    for (int k = 0; k < 64; ++k) {
        wr1[k] = Wc1[k * 64 + j];
        wr2[k] = Wc1[(64 + k) * 64 + j];
    }
    float bj = bc1[j];
    int n0 = blockIdx.x * G2;
    for (int n = n0; n < n0 + G2; n += 2) {
        const float* xr0 = hf + (size_t)n * 64;
        const float* xr1 = xr0 + 64;
        float a10 = bj, a20 = 0.f, a11 = bj, a21 = 0.f;
#pragma unroll
        for (int k = 0; k < 64; ++k) {
            a10 = fmaf(xr0[k], wr1[k], a10);
            a20 = fmaf(xr0[k], wr2[k], a20);
            a11 = fmaf(xr1[k], wr1[k], a11);
            a21 = fmaf(xr1[k], wr2[k], a21);
        }
        P1[(size_t)n * 64 + j] = a10;
        P2[(size_t)n * 64 + j] = a20;
        P1[(size_t)(n + 1) * 64 + j] = a11;
        P2[(size_t)(n + 1) * 64 + j] = a21;
    }
}

// ---------- edge attention contributions: a_e1[E,2], a_e2[E] ----------
__global__ void k_ae(const float* __restrict__ ea, const float* __restrict__ ve1,
                     const float* __restrict__ ve2, float* __restrict__ ae1, float* __restrict__ ae2) {
    int e = blockIdx.x * blockDim.x + threadIdx.x;
    if (e >= N_EDGES) return;
    float s0 = 0.f, s1 = 0.f, s2 = 0.f;
#pragma unroll
    for (int k = 0; k < 16; ++k) {
        float v = ea[e * 16 + k];
        s0 = fmaf(v, ve1[k * 2 + 0], s0);
        s1 = fmaf(v, ve1[k * 2 + 1], s1);
        s2 = fmaf(v, ve2[k], s2);
    }
    ae1[e * 2 + 0] = s0;
    ae1[e * 2 + 1] = s1;
    ae2[e] = s2;
}

// ---------- CSR build: histogram, scan, fill ----------
__global__ void k_hist(const int* __restrict__ dst, int* __restrict__ cnt) {
    int e = blockIdx.x * blockDim.x + threadIdx.x;
    if (e < N_EDGES) atomicAdd(&cnt[dst[e]], 1);
}

__global__ __launch_bounds__(1024) void k_scan(const int* __restrict__ cnt, int* __restrict__ rp,
                                               int* __restrict__ cursor) {
    __shared__ int part[1024];
    int t = threadIdx.x;
    const int CH = (N_NODES + 1023) / 1024;  // 49
    int base = t * CH;
    int s = 0;
    for (int i = 0; i < CH; ++i) {
        int idx = base + i;
        if (idx < N_NODES) s += cnt[idx];
    }
    part[t] = s;
    __syncthreads();
    for (int off = 1; off < 1024; off <<= 1) {
        int v = (t >= off) ? part[t - off] : 0;
        __syncthreads();
        part[t] += v;
        __syncthreads();
    }
    int run = (t > 0) ? part[t - 1] : 0;
    for (int i = 0; i < CH; ++i) {
        int idx = base + i;
        if (idx < N_NODES) {
            rp[idx] = run;
            cursor[idx] = run;
            run += cnt[idx];
        }
    }
    if (t == 1023) rp[N_NODES] = part[1023];
}

__global__ void k_fill(const int* __restrict__ dst, int* __restrict__ cursor, int* __restrict__ eord) {
    int e = blockIdx.x * blockDim.x + threadIdx.x;
    if (e < N_EDGES) {
        int p = atomicAdd(&cursor[dst[e]], 1);
        eord[p] = e;
    }
}

// ---------- fused per-dst softmax + gather aggregation + bias + ELU ----------
// Block per dst node. Pass1: segment max. Pass2: exp-sum. Pass3: staged aggregation.
template <int C, int H>
__global__ __launch_bounds__(C) void k_attn_gather(const int* __restrict__ rp, const int* __restrict__ eord,
                                                   const int* __restrict__ src, const float* __restrict__ a_s,
                                                   const float* __restrict__ a_d, const float* __restrict__ a_e,
                                                   const float* __restrict__ hfeat, const float* __restrict__ bias,
                                                   float* __restrict__ outp) {
    int n = blockIdx.x;
    int tid = threadIdx.x;
    int beg = rp[n], end = rp[n + 1];
    __shared__ int es[C];
    __shared__ float al[C * H];
    __shared__ float red[2 * H];
    float adn[H];
#pragma unroll
    for (int h = 0; h < H; ++h) adn[h] = a_d[n * H + h];

    // pass 1: segment max
    float mx[H];
#pragma unroll
    for (int h = 0; h < H; ++h) mx[h] = -3.4e38f;
    for (int i = beg + tid; i < end; i += C) {
        int e = eord[i];
        int s = src[e];
#pragma unroll
        for (int h = 0; h < H; ++h) {
            float z = a_s[s * H + h] + adn[h] + a_e[e * H + h];
            z = z > 0.f ? z : NEG_SLOPE * z;
            mx[h] = fmaxf(mx[h], z);
        }
    }
#pragma unroll
    for (int h = 0; h < H; ++h) mx[h] = wmax64(mx[h]);
    if constexpr (C == 128) {
        if ((tid & 63) == 0) {
#pragma unroll
            for (int h = 0; h < H; ++h) red[(tid >> 6) * H + h] = mx[h];
        }
        __syncthreads();
#pragma unroll
        for (int h = 0; h < H; ++h) mx[h] = fmaxf(red[h], red[H + h]);
    }

    // pass 2: exp-sum
    float sm[H];
#pragma unroll
    for (int h = 0; h < H; ++h) sm[h] = 0.f;
    for (int i = beg + tid; i < end; i += C) {
        int e = eord[i];
        int s = src[e];
#pragma unroll
        for (int h = 0; h < H; ++h) {
            float z = a_s[s * H + h] + adn[h] + a_e[e * H + h];
            z = z > 0.f ? z : NEG_SLOPE * z;
            sm[h] += __expf(z - mx[h]);
        }
    }
#pragma unroll
    for (int h = 0; h < H; ++h) sm[h] = wred64(sm[h]);
    if constexpr (C == 128) {
        __syncthreads();  // pass1 reads of red done
        if ((tid & 63) == 0) {
#pragma unroll
            for (int h = 0; h < H; ++h) red[(tid >> 6) * H + h] = sm[h];
        }
        __syncthreads();
#pragma unroll
        for (int h = 0; h < H; ++h) sm[h] = red[h] + red[H + h];
    }
    float dinv[H];
#pragma unroll
    for (int h = 0; h < H; ++h) dinv[h] = 1.f / (sm[h] + 1e-16f);

    // pass 3: staged weighted aggregation
    float acc = 0.f;
    const int hsel = (H == 2) ? (tid >> 6) : 0;
    for (int base = beg; base < end; base += C) {
        int cnt = min(C, end - base);
        __syncthreads();
        if (tid < cnt) {
            int e = eord[base + tid];
            int s = src[e];
            es[tid] = s;
#pragma unroll
            for (int h = 0; h < H; ++h) {
                float z = a_s[s * H + h] + adn[h] + a_e[e * H + h];
                z = z > 0.f ? z : NEG_SLOPE * z;
                al[tid * H + h] = __expf(z - mx[h]) * dinv[h];
            }
        }
        __syncthreads();
#pragma unroll 4
        for (int i = 0; i < cnt; ++i) acc = fmaf(hfeat[(size_t)es[i] * C + tid], al[i * H + hsel], acc);
    }
    float v = acc + bias[tid];
    outp[(size_t)n * C + tid] = v > 0.f ? v : expm1f(v);
}

// ---------- classifier edge-side, CSR-grouped: warp per dst segment ----------
__global__ __launch_bounds__(256) void k_final(const int* __restrict__ rp, const int* __restrict__ eord,
                                               const int* __restrict__ src, const float* __restrict__ ea,
                                               const float* __restrict__ P1, const float* __restrict__ P2,
                                               const float* __restrict__ Wc1, const float* __restrict__ Wc2,
                                               const float* __restrict__ bc2, float* __restrict__ out) {
    __shared__ float wc1c[16 * 64];
    __shared__ float wc2s[64];
    int tid = threadIdx.x;
    for (int i = tid; i < 16 * 64; i += 256) wc1c[i] = Wc1[128 * 64 + i];
    if (tid < 64) wc2s[tid] = Wc2[tid];
    __syncthreads();
    int wid = tid >> 6, lane = tid & 63;
    int n = blockIdx.x * 4 + wid;
    if (n >= N_NODES) return;
    int beg = __builtin_amdgcn_readfirstlane(rp[n]);
    int end = __builtin_amdgcn_readfirstlane(rp[n + 1]);
    if (beg >= end) return;
    float p2 = P2[(size_t)n * 64 + lane];
    float bc = bc2[0];
    // software-pipelined: prefetch next edge's scalar chain during compute
    int e = __builtin_amdgcn_readfirstlane(eord[beg]);
    int s = __builtin_amdgcn_readfirstlane(src[e]);
    for (int i = beg; i < end; ++i) {
        int i2 = i + 1;
        int e2 = 0, s2 = 0;
        if (i2 < end) {
            e2 = __builtin_amdgcn_readfirstlane(eord[i2]);
            s2 = __builtin_amdgcn_readfirstlane(src[e2]);
        }
        float hid = p2 + P1[(size_t)s * 64 + lane];
        const float* eap = ea + (size_t)e * 16;
#pragma unroll
        for (int k = 0; k < 16; ++k) hid = fmaf(eap[k], wc1c[k * 64 + lane], hid);
        hid = fmaxf(hid, 0.f);
        float v = wred64(hid * wc2s[lane]);
        if (lane == 0) out[e] = v + bc;
        e = e2;
        s = s2;
    }
}

extern "C" void kernel_launch(void* const* d_in, const int* in_sizes, int n_in,
                              void* d_out, int out_size, void* d_ws, size_t ws_size,
                              hipStream_t stream) {
    const float* x     = (const float*)d_in[0];
    const int*   eidx  = (const int*)d_in[1];
    const float* ea    = (const float*)d_in[2];
    const float* W1    = (const float*)d_in[3];
    const float* atts1 = (const float*)d_in[4];
    const float* attd1 = (const float*)d_in[5];
    const float* We1   = (const float*)d_in[6];
    const float* atte1 = (const float*)d_in[7];
    const float* b1    = (const float*)d_in[8];
    const float* W2    = (const float*)d_in[9];
    const float* atts2 = (const float*)d_in[10];
    const float* attd2 = (const float*)d_in[11];
    const float* We2   = (const float*)d_in[12];
    const float* atte2 = (const float*)d_in[13];
    const float* b2    = (const float*)d_in[14];
    const float* Wc1   = (const float*)d_in[15];
    const float* bc1   = (const float*)d_in[16];
    const float* Wc2   = (const float*)d_in[17];
    const float* bc2   = (const float*)d_in[18];
    const int* srcp = eidx;
    const int* dstp = eidx + N_EDGES;
    float* out = (float*)d_out;

    char* w = (char*)d_ws;
    size_t off = 0;
    auto alloc = [&](size_t bytes) -> void* {
        void* p = w + off;
        off += (bytes + 255) & ~size_t(255);
        return p;
    };

    float* h1   = (float*)alloc(N_NODES * 128 * sizeof(float));  // conv1 features; later h2 / P1 / P2
    float* as1  = (float*)alloc(N_NODES * 2 * sizeof(float));
    float* ad1  = (float*)alloc(N_NODES * 2 * sizeof(float));
    float* ae1  = (float*)alloc(N_EDGES * 2 * sizeof(float));
    float* ae2  = (float*)alloc(N_EDGES * sizeof(float));
    float* as2  = (float*)alloc(N_NODES * sizeof(float));
    float* ad2  = (float*)alloc(N_NODES * sizeof(float));
    float* ve1  = (float*)alloc(32 * sizeof(float));
    float* ve2  = (float*)alloc(16 * sizeof(float));
    int*   rp     = (int*)alloc((N_NODES + 1) * sizeof(int));
    int*   eord   = (int*)alloc(N_EDGES * sizeof(int));
    int*   cursor = (int*)alloc(N_NODES * sizeof(int));
    float* out1   = (float*)alloc(N_NODES * 128 * sizeof(float));
    float* out2   = (float*)alloc(N_NODES * 64 * sizeof(float));

    // aliases (lifetime-disjoint, all within h1's 25.6MB region)
    float* h2 = h1;              // [N,64]: written by k_gemm2 after h1's last read (gather1 pass3)
    float* P1 = h1;              // [N,64]: written by k_p12 after h2's last read (gather2 pass3)
    float* P2 = h1 + (size_t)N_NODES * 64;

    // zeroed-every-call region
    char* zstart = w + off;
    int* cnt = (int*)alloc(N_NODES * sizeof(int));
    size_t zbytes = (size_t)((w + off) - zstart);
    hipMemsetAsync(zstart, 0, zbytes, stream);

    const int EB = (N_EDGES + 255) / 256;  // 3125

    // CSR build (shared by both conv layers + classifier)
    k_hist<<<EB, 256, 0, stream>>>(dstp, cnt);
    k_scan<<<1, 1024, 0, stream>>>(cnt, rp, cursor);
    k_fill<<<EB, 256, 0, stream>>>(dstp, cursor, eord);

    k_ve<<<1, 64, 0, stream>>>(We1, atte1, We2, atte2, ve1, ve2);
    k_gemm1<<<N_NODES / G1, 128, 0, stream>>>(x, W1, atts1, attd1, h1, as1, ad1);
    k_ae<<<EB, 256, 0, stream>>>(ea, ve1, ve2, ae1, ae2);

    // conv1: fused softmax + aggregate + bias + ELU
    k_attn_gather<128, 2><<<N_NODES, 128, 0, stream>>>(rp, eord, srcp, as1, ad1, ae1, h1, b1, out1);

    // conv2
    k_gemm2<<<N_NODES / G2, 64, 0, stream>>>(out1, W2, atts2, attd2, h2, as2, ad2);
    k_attn_gather<64, 1><<<N_NODES, 64, 0, stream>>>(rp, eord, srcp, as2, ad2, ae2, h2, b2, out2);

    // edge classifier
    k_p12<<<N_NODES / G2, 64, 0, stream>>>(out2, Wc1, bc1, P1, P2);
    k_final<<<(N_NODES + 3) / 4, 256, 0, stream>>>(rp, eord, srcp, ea, P1, P2, Wc1, Wc2, bc2, out);
}

// Round 5
// 738.768 us; speedup vs baseline: 3.8561x; 1.1319x over previous
//
#include <hip/hip_runtime.h>
#include <math.h>

#define N_NODES 50000
#define N_EDGES 800000
#define NEG_SLOPE 0.2f

// ---------- helpers ----------
__device__ __forceinline__ float wred64(float v) {
#pragma unroll
    for (int off = 32; off > 0; off >>= 1) v += __shfl_xor(v, off, 64);
    return v;
}
__device__ __forceinline__ float wmax64(float v) {
#pragma unroll
    for (int off = 32; off > 0; off >>= 1) v = fmaxf(v, __shfl_xor(v, off, 64));
    return v;
}

// ---------- tiny precompute: ve1[16][2], ve2[16] ----------
__global__ void k_ve(const float* __restrict__ We1, const float* __restrict__ atte1,
                     const float* __restrict__ We2, const float* __restrict__ atte2,
                     float* __restrict__ ve1, float* __restrict__ ve2) {
    int t = threadIdx.x;
    if (t < 32) {
        int k = t >> 1, h = t & 1;
        float s = 0.f;
        for (int c = 0; c < 64; ++c) s = fmaf(We1[k * 128 + h * 64 + c], atte1[h * 64 + c], s);
        ve1[k * 2 + h] = s;
    } else if (t < 48) {
        int k = t - 32;
        float s = 0.f;
        for (int c = 0; c < 64; ++c) s = fmaf(We2[k * 64 + c], atte2[c], s);
        ve2[k] = s;
    }
}

// ---------- conv1 node transform: h1 = x @ W1 (128->128), a_s1/a_d1 ----------
// W column in 128 VGPRs; grid-stride by 2 nodes; grid sized to VGPR-limited occupancy.
#define GRID1 1536
__global__ __launch_bounds__(128) void k_gemm1(const float* __restrict__ x, const float* __restrict__ W1,
                                               const float* __restrict__ atts, const float* __restrict__ attd,
                                               float* __restrict__ h1, float* __restrict__ a_s,
                                               float* __restrict__ a_d) {
    int j = threadIdx.x;
    int head = j >> 6;
    float wr[128];
#pragma unroll
    for (int k = 0; k < 128; ++k) wr[k] = W1[k * 128 + j];
    float asj = atts[j], adj = attd[j];
    for (int n = blockIdx.x * 2; n < N_NODES; n += GRID1 * 2) {
        const float* xr0 = x + (size_t)n * 128;
        const float* xr1 = xr0 + 128;
        float a0 = 0.f, a1 = 0.f;
#pragma unroll
        for (int k = 0; k < 128; ++k) {
            a0 = fmaf(xr0[k], wr[k], a0);
            a1 = fmaf(xr1[k], wr[k], a1);
        }
        h1[(size_t)n * 128 + j] = a0;
        h1[(size_t)(n + 1) * 128 + j] = a1;
        float ps0 = wred64(a0 * asj), pd0 = wred64(a0 * adj);
        float ps1 = wred64(a1 * asj), pd1 = wred64(a1 * adj);
        if ((j & 63) == 0) {
            a_s[n * 2 + head] = ps0;
            a_d[n * 2 + head] = pd0;
            a_s[(n + 1) * 2 + head] = ps1;
            a_d[(n + 1) * 2 + head] = pd1;
        }
    }
}

// ---------- conv2 node transform: h2 = h2in @ W2 (128->64), a_s2/a_d2 ----------
#define GRID2 3072
__global__ __launch_bounds__(64) void k_gemm2(const float* __restrict__ xin, const float* __restrict__ W,
                                              const float* __restrict__ atts, const float* __restrict__ attd,
                                              float* __restrict__ h2, float* __restrict__ a_s,
                                              float* __restrict__ a_d) {
    int j = threadIdx.x;
    float wr[128];
#pragma unroll
    for (int k = 0; k < 128; ++k) wr[k] = W[k * 64 + j];
    float asj = atts[j], adj = attd[j];
    for (int n = blockIdx.x * 2; n < N_NODES; n += GRID2 * 2) {
        const float* xr0 = xin + (size_t)n * 128;
        const float* xr1 = xr0 + 128;
        float a0 = 0.f, a1 = 0.f;
#pragma unroll
        for (int k = 0; k < 128; ++k) {
            a0 = fmaf(xr0[k], wr[k], a0);
            a1 = fmaf(xr1[k], wr[k], a1);
        }
        h2[(size_t)n * 64 + j] = a0;
        h2[(size_t)(n + 1) * 64 + j] = a1;
        float ps0 = wred64(a0 * asj), pd0 = wred64(a0 * adj);
        float ps1 = wred64(a1 * asj), pd1 = wred64(a1 * adj);
        if (j == 0) {
            a_s[n] = ps0;
            a_d[n] = pd0;
            a_s[n + 1] = ps1;
            a_d[n + 1] = pd1;
        }
    }
}

// ---------- classifier node-side: P1 = hf@Wc1[0:64]+bc1, P2 = hf@Wc1[64:128] ----------
__global__ __launch_bounds__(64) void k_p12(const float* __restrict__ hf, const float* __restrict__ Wc1,
                                            const float* __restrict__ bc1, float* __restrict__ P1,
                                            float* __restrict__ P2) {
    int j = threadIdx.x;
    float wr1[64], wr2[64];
#pragma unroll
    for (int k = 0; k < 64; ++k) {
        wr1[k] = Wc1[k * 64 + j];
        wr2[k] = Wc1[(64 + k) * 64 + j];
    }
    float bj = bc1[j];
    for (int n = blockIdx.x * 2; n < N_NODES; n += GRID2 * 2) {
        const float* xr0 = hf + (size_t)n * 64;
        const float* xr1 = xr0 + 64;
        float a10 = bj, a20 = 0.f, a11 = bj, a21 = 0.f;
#pragma unroll
        for (int k = 0; k < 64; ++k) {
            a10 = fmaf(xr0[k], wr1[k], a10);
            a20 = fmaf(xr0[k], wr2[k], a20);
            a11 = fmaf(xr1[k], wr1[k], a11);
            a21 = fmaf(xr1[k], wr2[k], a21);
        }
        P1[(size_t)n * 64 + j] = a10;
        P2[(size_t)n * 64 + j] = a20;
        P1[(size_t)(n + 1) * 64 + j] = a11;
        P2[(size_t)(n + 1) * 64 + j] = a21;
    }
}

// ---------- edge attention contributions: a_e1[E,2], a_e2[E] ----------
__global__ void k_ae(const float* __restrict__ ea, const float* __restrict__ ve1,
                     const float* __restrict__ ve2, float* __restrict__ ae1, float* __restrict__ ae2) {
    int e = blockIdx.x * blockDim.x + threadIdx.x;
    if (e >= N_EDGES) return;
    float s0 = 0.f, s1 = 0.f, s2 = 0.f;
#pragma unroll
    for (int k = 0; k < 16; ++k) {
        float v = ea[e * 16 + k];
        s0 = fmaf(v, ve1[k * 2 + 0], s0);
        s1 = fmaf(v, ve1[k * 2 + 1], s1);
        s2 = fmaf(v, ve2[k], s2);
    }
    ae1[e * 2 + 0] = s0;
    ae1[e * 2 + 1] = s1;
    ae2[e] = s2;
}

// ---------- CSR build: histogram, scan, fill ----------
__global__ void k_hist(const int* __restrict__ dst, int* __restrict__ cnt) {
    int e = blockIdx.x * blockDim.x + threadIdx.x;
    if (e < N_EDGES) atomicAdd(&cnt[dst[e]], 1);
}

__global__ __launch_bounds__(1024) void k_scan(const int* __restrict__ cnt, int* __restrict__ rp,
                                               int* __restrict__ cursor) {
    __shared__ int part[1024];
    int t = threadIdx.x;
    const int CH = (N_NODES + 1023) / 1024;  // 49
    int base = t * CH;
    int s = 0;
    for (int i = 0; i < CH; ++i) {
        int idx = base + i;
        if (idx < N_NODES) s += cnt[idx];
    }
    part[t] = s;
    __syncthreads();
    for (int off = 1; off < 1024; off <<= 1) {
        int v = (t >= off) ? part[t - off] : 0;
        __syncthreads();
        part[t] += v;
        __syncthreads();
    }
    int run = (t > 0) ? part[t - 1] : 0;
    for (int i = 0; i < CH; ++i) {
        int idx = base + i;
        if (idx < N_NODES) {
            rp[idx] = run;
            cursor[idx] = run;
            run += cnt[idx];
        }
    }
    if (t == 1023) rp[N_NODES] = part[1023];
}

__global__ void k_fill(const int* __restrict__ dst, int* __restrict__ cursor, int* __restrict__ eord) {
    int e = blockIdx.x * blockDim.x + threadIdx.x;
    if (e < N_EDGES) {
        int p = atomicAdd(&cursor[dst[e]], 1);
        eord[p] = e;
    }
}

// ---------- fused per-dst softmax + gather aggregation + bias + ELU ----------
// Block per dst node. Pass1: segment max. Pass2: exp-sum. Pass3: staged aggregation.
template <int C, int H>
__global__ __launch_bounds__(C) void k_attn_gather(const int* __restrict__ rp, const int* __restrict__ eord,
                                                   const int* __restrict__ src, const float* __restrict__ a_s,
                                                   const float* __restrict__ a_d, const float* __restrict__ a_e,
                                                   const float* __restrict__ hfeat, const float* __restrict__ bias,
                                                   float* __restrict__ outp) {
    int n = blockIdx.x;
    int tid = threadIdx.x;
    int beg = rp[n], end = rp[n + 1];
    __shared__ int es[C];
    __shared__ float al[C * H];
    __shared__ float red[2 * H];
    float adn[H];
#pragma unroll
    for (int h = 0; h < H; ++h) adn[h] = a_d[n * H + h];

    // pass 1: segment max
    float mx[H];
#pragma unroll
    for (int h = 0; h < H; ++h) mx[h] = -3.4e38f;
    for (int i = beg + tid; i < end; i += C) {
        int e = eord[i];
        int s = src[e];
#pragma unroll
        for (int h = 0; h < H; ++h) {
            float z = a_s[s * H + h] + adn[h] + a_e[e * H + h];
            z = z > 0.f ? z : NEG_SLOPE * z;
            mx[h] = fmaxf(mx[h], z);
        }
    }
#pragma unroll
    for (int h = 0; h < H; ++h) mx[h] = wmax64(mx[h]);
    if constexpr (C == 128) {
        if ((tid & 63) == 0) {
#pragma unroll
            for (int h = 0; h < H; ++h) red[(tid >> 6) * H + h] = mx[h];
        }
        __syncthreads();
#pragma unroll
        for (int h = 0; h < H; ++h) mx[h] = fmaxf(red[h], red[H + h]);
    }

    // pass 2: exp-sum
    float sm[H];
#pragma unroll
    for (int h = 0; h < H; ++h) sm[h] = 0.f;
    for (int i = beg + tid; i < end; i += C) {
        int e = eord[i];
        int s = src[e];
#pragma unroll
        for (int h = 0; h < H; ++h) {
            float z = a_s[s * H + h] + adn[h] + a_e[e * H + h];
            z = z > 0.f ? z : NEG_SLOPE * z;
            sm[h] += __expf(z - mx[h]);
        }
    }
#pragma unroll
    for (int h = 0; h < H; ++h) sm[h] = wred64(sm[h]);
    if constexpr (C == 128) {
        __syncthreads();  // pass1 reads of red done
        if ((tid & 63) == 0) {
#pragma unroll
            for (int h = 0; h < H; ++h) red[(tid >> 6) * H + h] = sm[h];
        }
        __syncthreads();
#pragma unroll
        for (int h = 0; h < H; ++h) sm[h] = red[h] + red[H + h];
    }
    float dinv[H];
#pragma unroll
    for (int h = 0; h < H; ++h) dinv[h] = 1.f / (sm[h] + 1e-16f);

    // pass 3: staged weighted aggregation
    float acc = 0.f;
    const int hsel = (H == 2) ? (tid >> 6) : 0;
    for (int base = beg; base < end; base += C) {
        int cnt = min(C, end - base);
        __syncthreads();
        if (tid < cnt) {
            int e = eord[base + tid];
            int s = src[e];
            es[tid] = s;
#pragma unroll
            for (int h = 0; h < H; ++h) {
                float z = a_s[s * H + h] + adn[h] + a_e[e * H + h];
                z = z > 0.f ? z : NEG_SLOPE * z;
                al[tid * H + h] = __expf(z - mx[h]) * dinv[h];
            }
        }
        __syncthreads();
#pragma unroll 4
        for (int i = 0; i < cnt; ++i) acc = fmaf(hfeat[(size_t)es[i] * C + tid], al[i * H + hsel], acc);
    }
    float v = acc + bias[tid];
    outp[(size_t)n * C + tid] = v > 0.f ? v : expm1f(v);
}

// ---------- classifier edge-side, CSR-grouped: warp per dst segment ----------
__global__ __launch_bounds__(256) void k_final(const int* __restrict__ rp, const int* __restrict__ eord,
                                               const int* __restrict__ src, const float* __restrict__ ea,
                                               const float* __restrict__ P1, const float* __restrict__ P2,
                                               const float* __restrict__ Wc1, const float* __restrict__ Wc2,
                                               const float* __restrict__ bc2, float* __restrict__ out) {
    __shared__ float wc1c[16 * 64];
    __shared__ float wc2s[64];
    int tid = threadIdx.x;
    for (int i = tid; i < 16 * 64; i += 256) wc1c[i] = Wc1[128 * 64 + i];
    if (tid < 64) wc2s[tid] = Wc2[tid];
    __syncthreads();
    int wid = tid >> 6, lane = tid & 63;
    int n = blockIdx.x * 4 + wid;
    if (n >= N_NODES) return;
    int beg = __builtin_amdgcn_readfirstlane(rp[n]);
    int end = __builtin_amdgcn_readfirstlane(rp[n + 1]);
    if (beg >= end) return;
    float p2 = P2[(size_t)n * 64 + lane];
    float bc = bc2[0];
    // software-pipelined: prefetch next edge's scalar chain during compute
    int e = __builtin_amdgcn_readfirstlane(eord[beg]);
    int s = __builtin_amdgcn_readfirstlane(src[e]);
    for (int i = beg; i < end; ++i) {
        int i2 = i + 1;
        int e2 = 0, s2 = 0;
        if (i2 < end) {
            e2 = __builtin_amdgcn_readfirstlane(eord[i2]);
            s2 = __builtin_amdgcn_readfirstlane(src[e2]);
        }
        float hid = p2 + P1[(size_t)s * 64 + lane];
        const float* eap = ea + (size_t)e * 16;
#pragma unroll
        for (int k = 0; k < 16; ++k) hid = fmaf(eap[k], wc1c[k * 64 + lane], hid);
        hid = fmaxf(hid, 0.f);
        float v = wred64(hid * wc2s[lane]);
        if (lane == 0) out[e] = v + bc;
        e = e2;
        s = s2;
    }
}

extern "C" void kernel_launch(void* const* d_in, const int* in_sizes, int n_in,
                              void* d_out, int out_size, void* d_ws, size_t ws_size,
                              hipStream_t stream) {
    const float* x     = (const float*)d_in[0];
    const int*   eidx  = (const int*)d_in[1];
    const float* ea    = (const float*)d_in[2];
    const float* W1    = (const float*)d_in[3];
    const float* atts1 = (const float*)d_in[4];
    const float* attd1 = (const float*)d_in[5];
    const float* We1   = (const float*)d_in[6];
    const float* atte1 = (const float*)d_in[7];
    const float* b1    = (const float*)d_in[8];
    const float* W2    = (const float*)d_in[9];
    const float* atts2 = (const float*)d_in[10];
    const float* attd2 = (const float*)d_in[11];
    const float* We2   = (const float*)d_in[12];
    const float* atte2 = (const float*)d_in[13];
    const float* b2    = (const float*)d_in[14];
    const float* Wc1   = (const float*)d_in[15];
    const float* bc1   = (const float*)d_in[16];
    const float* Wc2   = (const float*)d_in[17];
    const float* bc2   = (const float*)d_in[18];
    const int* srcp = eidx;
    const int* dstp = eidx + N_EDGES;
    float* out = (float*)d_out;

    char* w = (char*)d_ws;
    size_t off = 0;
    auto alloc = [&](size_t bytes) -> void* {
        void* p = w + off;
        off += (bytes + 255) & ~size_t(255);
        return p;
    };

    float* h1   = (float*)alloc(N_NODES * 128 * sizeof(float));  // conv1 features; later h2 / P1 / P2
    float* as1  = (float*)alloc(N_NODES * 2 * sizeof(float));
    float* ad1  = (float*)alloc(N_NODES * 2 * sizeof(float));
    float* ae1  = (float*)alloc(N_EDGES * 2 * sizeof(float));
    float* ae2  = (float*)alloc(N_EDGES * sizeof(float));
    float* as2  = (float*)alloc(N_NODES * sizeof(float));
    float* ad2  = (float*)alloc(N_NODES * sizeof(float));
    float* ve1  = (float*)alloc(32 * sizeof(float));
    float* ve2  = (float*)alloc(16 * sizeof(float));
    int*   rp     = (int*)alloc((N_NODES + 1) * sizeof(int));
    int*   eord   = (int*)alloc(N_EDGES * sizeof(int));
    int*   cursor = (int*)alloc(N_NODES * sizeof(int));
    float* out1   = (float*)alloc(N_NODES * 128 * sizeof(float));
    float* out2   = (float*)alloc(N_NODES * 64 * sizeof(float));

    // aliases (lifetime-disjoint, all within h1's 25.6MB region)
    float* h2 = h1;              // [N,64]: written by k_gemm2 after h1's last read (gather1 pass3)
    float* P1 = h1;              // [N,64]: written by k_p12 after h2's last read (gather2 pass3)
    float* P2 = h1 + (size_t)N_NODES * 64;

    // zeroed-every-call region
    char* zstart = w + off;
    int* cnt = (int*)alloc(N_NODES * sizeof(int));
    size_t zbytes = (size_t)((w + off) - zstart);
    hipMemsetAsync(zstart, 0, zbytes, stream);

    const int EB = (N_EDGES + 255) / 256;  // 3125

    // CSR build (shared by both conv layers + classifier)
    k_hist<<<EB, 256, 0, stream>>>(dstp, cnt);
    k_scan<<<1, 1024, 0, stream>>>(cnt, rp, cursor);
    k_fill<<<EB, 256, 0, stream>>>(dstp, cursor, eord);

    k_ve<<<1, 64, 0, stream>>>(We1, atte1, We2, atte2, ve1, ve2);
    k_gemm1<<<GRID1, 128, 0, stream>>>(x, W1, atts1, attd1, h1, as1, ad1);
    k_ae<<<EB, 256, 0, stream>>>(ea, ve1, ve2, ae1, ae2);

    // conv1: fused softmax + aggregate + bias + ELU
    k_attn_gather<128, 2><<<N_NODES, 128, 0, stream>>>(rp, eord, srcp, as1, ad1, ae1, h1, b1, out1);

    // conv2
    k_gemm2<<<GRID2, 64, 0, stream>>>(out1, W2, atts2, attd2, h2, as2, ad2);
    k_attn_gather<64, 1><<<N_NODES, 64, 0, stream>>>(rp, eord, srcp, as2, ad2, ae2, h2, b2, out2);

    // edge classifier
    k_p12<<<GRID2, 64, 0, stream>>>(out2, Wc1, bc1, P1, P2);
    k_final<<<(N_NODES + 3) / 4, 256, 0, stream>>>(rp, eord, srcp, ea, P1, P2, Wc1, Wc2, bc2, out);
}

// Round 6
// 673.057 us; speedup vs baseline: 4.2326x; 1.0976x over previous
//
#include <hip/hip_runtime.h>
#include <math.h>

#define N_NODES 50000
#define N_EDGES 800000
#define NEG_SLOPE 0.2f

// ---------- helpers ----------
__device__ __forceinline__ float wred64(float v) {
#pragma unroll
    for (int off = 32; off > 0; off >>= 1) v += __shfl_xor(v, off, 64);
    return v;
}
__device__ __forceinline__ float wmax64(float v) {
#pragma unroll
    for (int off = 32; off > 0; off >>= 1) v = fmaxf(v, __shfl_xor(v, off, 64));
    return v;
}

// ---------- tiny precompute: ve1[16][2], ve2[16] ----------
__global__ void k_ve(const float* __restrict__ We1, const float* __restrict__ atte1,
                     const float* __restrict__ We2, const float* __restrict__ atte2,
                     float* __restrict__ ve1, float* __restrict__ ve2) {
    int t = threadIdx.x;
    if (t < 32) {
        int k = t >> 1, h = t & 1;
        float s = 0.f;
        for (int c = 0; c < 64; ++c) s = fmaf(We1[k * 128 + h * 64 + c], atte1[h * 64 + c], s);
        ve1[k * 2 + h] = s;
    } else if (t < 48) {
        int k = t - 32;
        float s = 0.f;
        for (int c = 0; c < 64; ++c) s = fmaf(We2[k * 64 + c], atte2[c], s);
        ve2[k] = s;
    }
}

// ---------- conv1 node transform: h1 = x @ W1 (128->128), a_s1/a_d1 ----------
#define GRID1 1536
__global__ __launch_bounds__(128) void k_gemm1(const float* __restrict__ x, const float* __restrict__ W1,
                                               const float* __restrict__ atts, const float* __restrict__ attd,
                                               float* __restrict__ h1, float* __restrict__ a_s,
                                               float* __restrict__ a_d) {
    int j = threadIdx.x;
    int head = j >> 6;
    float wr[128];
#pragma unroll
    for (int k = 0; k < 128; ++k) wr[k] = W1[k * 128 + j];
    float asj = atts[j], adj = attd[j];
    for (int n = blockIdx.x * 2; n < N_NODES; n += GRID1 * 2) {
        const float* xr0 = x + (size_t)n * 128;
        const float* xr1 = xr0 + 128;
        float a0 = 0.f, a1 = 0.f;
#pragma unroll
        for (int k = 0; k < 128; ++k) {
            a0 = fmaf(xr0[k], wr[k], a0);
            a1 = fmaf(xr1[k], wr[k], a1);
        }
        h1[(size_t)n * 128 + j] = a0;
        h1[(size_t)(n + 1) * 128 + j] = a1;
        float ps0 = wred64(a0 * asj), pd0 = wred64(a0 * adj);
        float ps1 = wred64(a1 * asj), pd1 = wred64(a1 * adj);
        if ((j & 63) == 0) {
            a_s[n * 2 + head] = ps0;
            a_d[n * 2 + head] = pd0;
            a_s[(n + 1) * 2 + head] = ps1;
            a_d[(n + 1) * 2 + head] = pd1;
        }
    }
}

// ---------- conv2 node transform: h2 = h2in @ W2 (128->64), a_s2/a_d2 ----------
#define GRID2 3072
__global__ __launch_bounds__(64) void k_gemm2(const float* __restrict__ xin, const float* __restrict__ W,
                                              const float* __restrict__ atts, const float* __restrict__ attd,
                                              float* __restrict__ h2, float* __restrict__ a_s,
                                              float* __restrict__ a_d) {
    int j = threadIdx.x;
    float wr[128];
#pragma unroll
    for (int k = 0; k < 128; ++k) wr[k] = W[k * 64 + j];
    float asj = atts[j], adj = attd[j];
    for (int n = blockIdx.x * 2; n < N_NODES; n += GRID2 * 2) {
        const float* xr0 = xin + (size_t)n * 128;
        const float* xr1 = xr0 + 128;
        float a0 = 0.f, a1 = 0.f;
#pragma unroll
        for (int k = 0; k < 128; ++k) {
            a0 = fmaf(xr0[k], wr[k], a0);
            a1 = fmaf(xr1[k], wr[k], a1);
        }
        h2[(size_t)n * 64 + j] = a0;
        h2[(size_t)(n + 1) * 64 + j] = a1;
        float ps0 = wred64(a0 * asj), pd0 = wred64(a0 * adj);
        float ps1 = wred64(a1 * asj), pd1 = wred64(a1 * adj);
        if (j == 0) {
            a_s[n] = ps0;
            a_d[n] = pd0;
            a_s[n + 1] = ps1;
            a_d[n + 1] = pd1;
        }
    }
}

// ---------- classifier node-side: P1 = hf@Wc1[0:64]+bc1, P2 = hf@Wc1[64:128] ----------
__global__ __launch_bounds__(64) void k_p12(const float* __restrict__ hf, const float* __restrict__ Wc1,
                                            const float* __restrict__ bc1, float* __restrict__ P1,
                                            float* __restrict__ P2) {
    int j = threadIdx.x;
    float wr1[64], wr2[64];
#pragma unroll
    for (int k = 0; k < 64; ++k) {
        wr1[k] = Wc1[k * 64 + j];
        wr2[k] = Wc1[(64 + k) * 64 + j];
    }
    float bj = bc1[j];
    for (int n = blockIdx.x * 2; n < N_NODES; n += GRID2 * 2) {
        const float* xr0 = hf + (size_t)n * 64;
        const float* xr1 = xr0 + 64;
        float a10 = bj, a20 = 0.f, a11 = bj, a21 = 0.f;
#pragma unroll
        for (int k = 0; k < 64; ++k) {
            a10 = fmaf(xr0[k], wr1[k], a10);
            a20 = fmaf(xr0[k], wr2[k], a20);
            a11 = fmaf(xr1[k], wr1[k], a11);
            a21 = fmaf(xr1[k], wr2[k], a21);
        }
        P1[(size_t)n * 64 + j] = a10;
        P2[(size_t)n * 64 + j] = a20;
        P1[(size_t)(n + 1) * 64 + j] = a11;
        P2[(size_t)(n + 1) * 64 + j] = a21;
    }
}

// ---------- edge attention contributions: a_e1[E,2], a_e2[E] (edge order) ----------
__global__ void k_ae(const float* __restrict__ ea, const float* __restrict__ ve1,
                     const float* __restrict__ ve2, float* __restrict__ ae1, float* __restrict__ ae2) {
    int e = blockIdx.x * blockDim.x + threadIdx.x;
    if (e >= N_EDGES) return;
    float s0 = 0.f, s1 = 0.f, s2 = 0.f;
#pragma unroll
    for (int k = 0; k < 16; ++k) {
        float v = ea[e * 16 + k];
        s0 = fmaf(v, ve1[k * 2 + 0], s0);
        s1 = fmaf(v, ve1[k * 2 + 1], s1);
        s2 = fmaf(v, ve2[k], s2);
    }
    ae1[e * 2 + 0] = s0;
    ae1[e * 2 + 1] = s1;
    ae2[e] = s2;
}

// ---------- CSR build: histogram, scan, fill ----------
__global__ void k_hist(const int* __restrict__ dst, int* __restrict__ cnt) {
    int e = blockIdx.x * blockDim.x + threadIdx.x;
    if (e < N_EDGES) atomicAdd(&cnt[dst[e]], 1);
}

__global__ __launch_bounds__(1024) void k_scan(const int* __restrict__ cnt, int* __restrict__ rp,
                                               int* __restrict__ cursor) {
    __shared__ int part[1024];
    int t = threadIdx.x;
    const int CH = (N_NODES + 1023) / 1024;  // 49
    int base = t * CH;
    int s = 0;
    for (int i = 0; i < CH; ++i) {
        int idx = base + i;
        if (idx < N_NODES) s += cnt[idx];
    }
    part[t] = s;
    __syncthreads();
    for (int off = 1; off < 1024; off <<= 1) {
        int v = (t >= off) ? part[t - off] : 0;
        __syncthreads();
        part[t] += v;
        __syncthreads();
    }
    int run = (t > 0) ? part[t - 1] : 0;
    for (int i = 0; i < CH; ++i) {
        int idx = base + i;
        if (idx < N_NODES) {
            rp[idx] = run;
            cursor[idx] = run;
            run += cnt[idx];
        }
    }
    if (t == 1023) rp[N_NODES] = part[1023];
}

__global__ void k_fill(const int* __restrict__ dst, int* __restrict__ cursor, int* __restrict__ eord) {
    int e = blockIdx.x * blockDim.x + threadIdx.x;
    if (e < N_EDGES) {
        int p = atomicAdd(&cursor[dst[e]], 1);
        eord[p] = e;
    }
}

// ---------- CSR-ordered edge tables (one-time random gather) ----------
// zo1[i,h] = a_s1[src,h] + a_e1[e,h]   (a_d and leaky applied later, per-dst)
__global__ void k_prep1(const int* __restrict__ eord, const int* __restrict__ src,
                        const float* __restrict__ as1, const float* __restrict__ ae1,
                        int* __restrict__ src_ord, float* __restrict__ zo1) {
    int i = blockIdx.x * blockDim.x + threadIdx.x;
    if (i >= N_EDGES) return;
    int e = eord[i];
    int s = src[e];
    src_ord[i] = s;
    zo1[i * 2 + 0] = as1[s * 2 + 0] + ae1[e * 2 + 0];
    zo1[i * 2 + 1] = as1[s * 2 + 1] + ae1[e * 2 + 1];
}

__global__ void k_prep2(const int* __restrict__ eord, const int* __restrict__ src_ord,
                        const float* __restrict__ as2, const float* __restrict__ ae2,
                        float* __restrict__ zo2) {
    int i = blockIdx.x * blockDim.x + threadIdx.x;
    if (i >= N_EDGES) return;
    zo2[i] = as2[src_ord[i]] + ae2[eord[i]];
}

// ---------- fused per-dst softmax + gather aggregation + bias + ELU ----------
// Block per dst node; streams CSR-ordered zo/src_ord. 3 passes (max, sum, aggregate).
template <int C, int H>
__global__ __launch_bounds__(C) void k_attn_gather(const int* __restrict__ rp, const int* __restrict__ src_ord,
                                                   const float* __restrict__ zo, const float* __restrict__ a_d,
                                                   const float* __restrict__ hfeat, const float* __restrict__ bias,
                                                   float* __restrict__ outp) {
    int n = blockIdx.x;
    int tid = threadIdx.x;
    int beg = rp[n], end = rp[n + 1];
    __shared__ int es[C];
    __shared__ float al[C * H];
    __shared__ float red[2 * H];
    float adn[H];
#pragma unroll
    for (int h = 0; h < H; ++h) adn[h] = a_d[n * H + h];

    // pass 1: segment max (contiguous zo stream)
    float mx[H];
#pragma unroll
    for (int h = 0; h < H; ++h) mx[h] = -3.4e38f;
    for (int i = beg + tid; i < end; i += C) {
#pragma unroll
        for (int h = 0; h < H; ++h) {
            float z = zo[i * H + h] + adn[h];
            z = z > 0.f ? z : NEG_SLOPE * z;
            mx[h] = fmaxf(mx[h], z);
        }
    }
#pragma unroll
    for (int h = 0; h < H; ++h) mx[h] = wmax64(mx[h]);
    if constexpr (C == 128) {
        if ((tid & 63) == 0) {
#pragma unroll
            for (int h = 0; h < H; ++h) red[(tid >> 6) * H + h] = mx[h];
        }
        __syncthreads();
#pragma unroll
        for (int h = 0; h < H; ++h) mx[h] = fmaxf(red[h], red[H + h]);
    }

    // pass 2: exp-sum
    float sm[H];
#pragma unroll
    for (int h = 0; h < H; ++h) sm[h] = 0.f;
    for (int i = beg + tid; i < end; i += C) {
#pragma unroll
        for (int h = 0; h < H; ++h) {
            float z = zo[i * H + h] + adn[h];
            z = z > 0.f ? z : NEG_SLOPE * z;
            sm[h] += __expf(z - mx[h]);
        }
    }
#pragma unroll
    for (int h = 0; h < H; ++h) sm[h] = wred64(sm[h]);
    if constexpr (C == 128) {
        __syncthreads();  // pass1 reads of red done
        if ((tid & 63) == 0) {
#pragma unroll
            for (int h = 0; h < H; ++h) red[(tid >> 6) * H + h] = sm[h];
        }
        __syncthreads();
#pragma unroll
        for (int h = 0; h < H; ++h) sm[h] = red[h] + red[H + h];
    }
    float dinv[H];
#pragma unroll
    for (int h = 0; h < H; ++h) dinv[h] = 1.f / (sm[h] + 1e-16f);

    // pass 3: staged weighted aggregation (src_ord/zo contiguous; hfeat rows random but coalesced)
    float acc = 0.f;
    const int hsel = (H == 2) ? (tid >> 6) : 0;
    for (int base = beg; base < end; base += C) {
        int cnt = min(C, end - base);
        __syncthreads();
        if (tid < cnt) {
            int i = base + tid;
            es[tid] = src_ord[i];
#pragma unroll
            for (int h = 0; h < H; ++h) {
                float z = zo[i * H + h] + adn[h];
                z = z > 0.f ? z : NEG_SLOPE * z;
                al[tid * H + h] = __expf(z - mx[h]) * dinv[h];
            }
        }
        __syncthreads();
#pragma unroll 4
        for (int i = 0; i < cnt; ++i) acc = fmaf(hfeat[(size_t)es[i] * C + tid], al[i * H + hsel], acc);
    }
    float v = acc + bias[tid];
    outp[(size_t)n * C + tid] = v > 0.f ? v : expm1f(v);
}

// ---------- classifier edge-side, CSR-grouped: warp per dst segment, ILP-2 ----------
__global__ __launch_bounds__(256) void k_final(const int* __restrict__ rp, const int* __restrict__ eord,
                                               const int* __restrict__ src_ord, const float* __restrict__ ea,
                                               const float* __restrict__ P1, const float* __restrict__ P2,
                                               const float* __restrict__ Wc1, const float* __restrict__ Wc2,
                                               const float* __restrict__ bc2, float* __restrict__ out) {
    __shared__ float wc1c[16 * 64];
    __shared__ float wc2s[64];
    int tid = threadIdx.x;
    for (int i = tid; i < 16 * 64; i += 256) wc1c[i] = Wc1[128 * 64 + i];
    if (tid < 64) wc2s[tid] = Wc2[tid];
    __syncthreads();
    int wid = tid >> 6, lane = tid & 63;
    int n = blockIdx.x * 4 + wid;
    if (n >= N_NODES) return;
    int beg = __builtin_amdgcn_readfirstlane(rp[n]);
    int end = __builtin_amdgcn_readfirstlane(rp[n + 1]);
    if (beg >= end) return;
    float p2 = P2[(size_t)n * 64 + lane];
    float bc = bc2[0];
    float w2 = wc2s[lane];
    int i = beg;
    for (; i + 1 < end; i += 2) {
        int e0 = __builtin_amdgcn_readfirstlane(eord[i]);
        int e1 = __builtin_amdgcn_readfirstlane(eord[i + 1]);
        int s0 = __builtin_amdgcn_readfirstlane(src_ord[i]);
        int s1 = __builtin_amdgcn_readfirstlane(src_ord[i + 1]);
        float h0 = p2 + P1[(size_t)s0 * 64 + lane];
        float h1 = p2 + P1[(size_t)s1 * 64 + lane];
        const float* ea0 = ea + (size_t)e0 * 16;
        const float* ea1 = ea + (size_t)e1 * 16;
#pragma unroll
        for (int k = 0; k < 16; ++k) {
            float wv = wc1c[k * 64 + lane];
            h0 = fmaf(ea0[k], wv, h0);
            h1 = fmaf(ea1[k], wv, h1);
        }
        h0 = fmaxf(h0, 0.f) * w2;
        h1 = fmaxf(h1, 0.f) * w2;
#pragma unroll
        for (int off = 32; off > 0; off >>= 1) {
            h0 += __shfl_xor(h0, off, 64);
            h1 += __shfl_xor(h1, off, 64);
        }
        if (lane == 0) {
            out[e0] = h0 + bc;
            out[e1] = h1 + bc;
        }
    }
    if (i < end) {
        int e0 = __builtin_amdgcn_readfirstlane(eord[i]);
        int s0 = __builtin_amdgcn_readfirstlane(src_ord[i]);
        float h0 = p2 + P1[(size_t)s0 * 64 + lane];
        const float* ea0 = ea + (size_t)e0 * 16;
#pragma unroll
        for (int k = 0; k < 16; ++k) h0 = fmaf(ea0[k], wc1c[k * 64 + lane], h0);
        h0 = fmaxf(h0, 0.f);
        float v = wred64(h0 * w2);
        if (lane == 0) out[e0] = v + bc;
    }
}

extern "C" void kernel_launch(void* const* d_in, const int* in_sizes, int n_in,
                              void* d_out, int out_size, void* d_ws, size_t ws_size,
                              hipStream_t stream) {
    const float* x     = (const float*)d_in[0];
    const int*   eidx  = (const int*)d_in[1];
    const float* ea    = (const float*)d_in[2];
    const float* W1    = (const float*)d_in[3];
    const float* atts1 = (const float*)d_in[4];
    const float* attd1 = (const float*)d_in[5];
    const float* We1   = (const float*)d_in[6];
    const float* atte1 = (const float*)d_in[7];
    const float* b1    = (const float*)d_in[8];
    const float* W2    = (const float*)d_in[9];
    const float* atts2 = (const float*)d_in[10];
    const float* attd2 = (const float*)d_in[11];
    const float* We2   = (const float*)d_in[12];
    const float* atte2 = (const float*)d_in[13];
    const float* b2    = (const float*)d_in[14];
    const float* Wc1   = (const float*)d_in[15];
    const float* bc1   = (const float*)d_in[16];
    const float* Wc2   = (const float*)d_in[17];
    const float* bc2   = (const float*)d_in[18];
    const int* srcp = eidx;
    const int* dstp = eidx + N_EDGES;
    float* out = (float*)d_out;

    char* w = (char*)d_ws;
    size_t off = 0;
    auto alloc = [&](size_t bytes) -> void* {
        void* p = w + off;
        off += (bytes + 255) & ~size_t(255);
        return p;
    };

    float* h1   = (float*)alloc(N_NODES * 128 * sizeof(float));  // conv1 features; later h2 / P1 / P2
    float* as1  = (float*)alloc(N_NODES * 2 * sizeof(float));
    float* ad1  = (float*)alloc(N_NODES * 2 * sizeof(float));
    float* ae1  = (float*)alloc(N_EDGES * 2 * sizeof(float));    // dead after k_prep1; reused as zo2
    float* ae2  = (float*)alloc(N_EDGES * sizeof(float));
    float* as2  = (float*)alloc(N_NODES * sizeof(float));
    float* ad2  = (float*)alloc(N_NODES * sizeof(float));
    float* ve1  = (float*)alloc(32 * sizeof(float));
    float* ve2  = (float*)alloc(16 * sizeof(float));
    int*   rp      = (int*)alloc((N_NODES + 1) * sizeof(int));
    int*   eord    = (int*)alloc(N_EDGES * sizeof(int));
    int*   cursor  = (int*)alloc(N_NODES * sizeof(int));
    int*   src_ord = (int*)alloc(N_EDGES * sizeof(int));
    float* zo1     = (float*)alloc(N_EDGES * 2 * sizeof(float));
    float* out1    = (float*)alloc(N_NODES * 128 * sizeof(float));
    float* out2    = (float*)alloc(N_NODES * 64 * sizeof(float));

    // aliases (lifetime-disjoint)
    float* h2  = h1;              // [N,64]: gemm2 writes after h1's last read (gather1 pass3)
    float* P1  = h1;              // [N,64]: p12 writes after h2's last read (gather2 pass3)
    float* P2  = h1 + (size_t)N_NODES * 64;
    float* zo2 = ae1;             // [E]: prep2 writes after ae1's last read (prep1)

    // zeroed-every-call region
    char* zstart = w + off;
    int* cnt = (int*)alloc(N_NODES * sizeof(int));
    size_t zbytes = (size_t)((w + off) - zstart);
    hipMemsetAsync(zstart, 0, zbytes, stream);

    const int EB = (N_EDGES + 255) / 256;  // 3125

    // CSR build (shared by both conv layers + classifier)
    k_hist<<<EB, 256, 0, stream>>>(dstp, cnt);
    k_scan<<<1, 1024, 0, stream>>>(cnt, rp, cursor);
    k_fill<<<EB, 256, 0, stream>>>(dstp, cursor, eord);

    k_ve<<<1, 64, 0, stream>>>(We1, atte1, We2, atte2, ve1, ve2);
    k_gemm1<<<GRID1, 128, 0, stream>>>(x, W1, atts1, attd1, h1, as1, ad1);
    k_ae<<<EB, 256, 0, stream>>>(ea, ve1, ve2, ae1, ae2);

    // conv1: CSR-ordered tables, then fused softmax+aggregate+bias+ELU
    k_prep1<<<EB, 256, 0, stream>>>(eord, srcp, as1, ae1, src_ord, zo1);
    k_attn_gather<128, 2><<<N_NODES, 128, 0, stream>>>(rp, src_ord, zo1, ad1, h1, b1, out1);

    // conv2
    k_gemm2<<<GRID2, 64, 0, stream>>>(out1, W2, atts2, attd2, h2, as2, ad2);
    k_prep2<<<EB, 256, 0, stream>>>(eord, src_ord, as2, ae2, zo2);
    k_attn_gather<64, 1><<<N_NODES, 64, 0, stream>>>(rp, src_ord, zo2, ad2, h2, b2, out2);

    // edge classifier
    k_p12<<<GRID2, 64, 0, stream>>>(out2, Wc1, bc1, P1, P2);
    k_final<<<(N_NODES + 3) / 4, 256, 0, stream>>>(rp, eord, src_ord, ea, P1, P2, Wc1, Wc2, bc2, out);
}

// Round 7
// 546.581 us; speedup vs baseline: 5.2120x; 1.2314x over previous
//
#include <hip/hip_runtime.h>
#include <math.h>

#define N_NODES 50000
#define N_EDGES 800000
#define NEG_SLOPE 0.2f

// ---------- helpers ----------
__device__ __forceinline__ float wred64(float v) {
#pragma unroll
    for (int off = 32; off > 0; off >>= 1) v += __shfl_xor(v, off, 64);
    return v;
}
__device__ __forceinline__ float wmax64(float v) {
#pragma unroll
    for (int off = 32; off > 0; off >>= 1) v = fmaxf(v, __shfl_xor(v, off, 64));
    return v;
}
__device__ __forceinline__ int wredi64(int v) {
#pragma unroll
    for (int off = 32; off > 0; off >>= 1) v += __shfl_xor(v, off, 64);
    return v;
}

// ---------- tiny precompute: ve1[16][2], ve2[16] ----------
__global__ void k_ve(const float* __restrict__ We1, const float* __restrict__ atte1,
                     const float* __restrict__ We2, const float* __restrict__ atte2,
                     float* __restrict__ ve1, float* __restrict__ ve2) {
    int t = threadIdx.x;
    if (t < 32) {
        int k = t >> 1, h = t & 1;
        float s = 0.f;
        for (int c = 0; c < 64; ++c) s = fmaf(We1[k * 128 + h * 64 + c], atte1[h * 64 + c], s);
        ve1[k * 2 + h] = s;
    } else if (t < 48) {
        int k = t - 32;
        float s = 0.f;
        for (int c = 0; c < 64; ++c) s = fmaf(We2[k * 64 + c], atte2[c], s);
        ve2[k] = s;
    }
}

// ---------- conv1 node transform: h1 = x @ W1 (128->128), a_s1/a_d1 ----------
#define GRID1 1536
__global__ __launch_bounds__(128) void k_gemm1(const float* __restrict__ x, const float* __restrict__ W1,
                                               const float* __restrict__ atts, const float* __restrict__ attd,
                                               float* __restrict__ h1, float* __restrict__ a_s,
                                               float* __restrict__ a_d) {
    int j = threadIdx.x;
    int head = j >> 6;
    float wr[128];
#pragma unroll
    for (int k = 0; k < 128; ++k) wr[k] = W1[k * 128 + j];
    float asj = atts[j], adj = attd[j];
    for (int n = blockIdx.x * 2; n < N_NODES; n += GRID1 * 2) {
        const float* xr0 = x + (size_t)n * 128;
        const float* xr1 = xr0 + 128;
        float a0 = 0.f, a1 = 0.f;
#pragma unroll
        for (int k = 0; k < 128; ++k) {
            a0 = fmaf(xr0[k], wr[k], a0);
            a1 = fmaf(xr1[k], wr[k], a1);
        }
        h1[(size_t)n * 128 + j] = a0;
        h1[(size_t)(n + 1) * 128 + j] = a1;
        float ps0 = wred64(a0 * asj), pd0 = wred64(a0 * adj);
        float ps1 = wred64(a1 * asj), pd1 = wred64(a1 * adj);
        if ((j & 63) == 0) {
            a_s[n * 2 + head] = ps0;
            a_d[n * 2 + head] = pd0;
            a_s[(n + 1) * 2 + head] = ps1;
            a_d[(n + 1) * 2 + head] = pd1;
        }
    }
}

// ---------- conv2 node transform: h2 = h2in @ W2 (128->64), a_s2/a_d2 ----------
#define GRID2 3072
__global__ __launch_bounds__(64) void k_gemm2(const float* __restrict__ xin, const float* __restrict__ W,
                                              const float* __restrict__ atts, const float* __restrict__ attd,
                                              float* __restrict__ h2, float* __restrict__ a_s,
                                              float* __restrict__ a_d) {
    int j = threadIdx.x;
    float wr[128];
#pragma unroll
    for (int k = 0; k < 128; ++k) wr[k] = W[k * 64 + j];
    float asj = atts[j], adj = attd[j];
    for (int n = blockIdx.x * 2; n < N_NODES; n += GRID2 * 2) {
        const float* xr0 = xin + (size_t)n * 128;
        const float* xr1 = xr0 + 128;
        float a0 = 0.f, a1 = 0.f;
#pragma unroll
        for (int k = 0; k < 128; ++k) {
            a0 = fmaf(xr0[k], wr[k], a0);
            a1 = fmaf(xr1[k], wr[k], a1);
        }
        h2[(size_t)n * 64 + j] = a0;
        h2[(size_t)(n + 1) * 64 + j] = a1;
        float ps0 = wred64(a0 * asj), pd0 = wred64(a0 * adj);
        float ps1 = wred64(a1 * asj), pd1 = wred64(a1 * adj);
        if (j == 0) {
            a_s[n] = ps0;
            a_d[n] = pd0;
            a_s[n + 1] = ps1;
            a_d[n + 1] = pd1;
        }
    }
}

// ---------- classifier node-side: P1 = hf@Wc1[0:64]+bc1, P2 = hf@Wc1[64:128] ----------
__global__ __launch_bounds__(64) void k_p12(const float* __restrict__ hf, const float* __restrict__ Wc1,
                                            const float* __restrict__ bc1, float* __restrict__ P1,
                                            float* __restrict__ P2) {
    int j = threadIdx.x;
    float wr1[64], wr2[64];
#pragma unroll
    for (int k = 0; k < 64; ++k) {
        wr1[k] = Wc1[k * 64 + j];
        wr2[k] = Wc1[(64 + k) * 64 + j];
    }
    float bj = bc1[j];
    for (int n = blockIdx.x * 2; n < N_NODES; n += GRID2 * 2) {
        const float* xr0 = hf + (size_t)n * 64;
        const float* xr1 = xr0 + 64;
        float a10 = bj, a20 = 0.f, a11 = bj, a21 = 0.f;
#pragma unroll
        for (int k = 0; k < 64; ++k) {
            a10 = fmaf(xr0[k], wr1[k], a10);
            a20 = fmaf(xr0[k], wr2[k], a20);
            a11 = fmaf(xr1[k], wr1[k], a11);
            a21 = fmaf(xr1[k], wr2[k], a21);
        }
        P1[(size_t)n * 64 + j] = a10;
        P2[(size_t)n * 64 + j] = a20;
        P1[(size_t)(n + 1) * 64 + j] = a11;
        P2[(size_t)(n + 1) * 64 + j] = a21;
    }
}

// ---------- edge attention contributions: a_e1[E,2], a_e2[E] (edge order) ----------
__global__ void k_ae(const float* __restrict__ ea, const float* __restrict__ ve1,
                     const float* __restrict__ ve2, float* __restrict__ ae1, float* __restrict__ ae2) {
    int e = blockIdx.x * blockDim.x + threadIdx.x;
    if (e >= N_EDGES) return;
    float s0 = 0.f, s1 = 0.f, s2 = 0.f;
#pragma unroll
    for (int k = 0; k < 16; ++k) {
        float v = ea[e * 16 + k];
        s0 = fmaf(v, ve1[k * 2 + 0], s0);
        s1 = fmaf(v, ve1[k * 2 + 1], s1);
        s2 = fmaf(v, ve2[k], s2);
    }
    ae1[e * 2 + 0] = s0;
    ae1[e * 2 + 1] = s1;
    ae2[e] = s2;
}

// ---------- CSR build: histogram, hierarchical scan, fill ----------
#define SCAN_BLKS ((N_NODES + 255) / 256)  // 196

__global__ void k_hist(const int* __restrict__ dst, int* __restrict__ cnt) {
    int e = blockIdx.x * blockDim.x + threadIdx.x;
    if (e < N_EDGES) atomicAdd(&cnt[dst[e]], 1);
}

// stage 1: per-block (256-chunk) sums of cnt
__global__ __launch_bounds__(256) void k_scan1(const int* __restrict__ cnt, int* __restrict__ bsum) {
    int t = threadIdx.x;
    int idx = blockIdx.x * 256 + t;
    int v = (idx < N_NODES) ? cnt[idx] : 0;
    int w = wredi64(v);
    __shared__ int ws[4];
    if ((t & 63) == 0) ws[t >> 6] = w;
    __syncthreads();
    if (t == 0) bsum[blockIdx.x] = ws[0] + ws[1] + ws[2] + ws[3];
}

// stage 2: exclusive scan of the block sums (in place), single small block
__global__ __launch_bounds__(256) void k_scan2(int* __restrict__ bsum) {
    __shared__ int sh[256];
    int t = threadIdx.x;
    int v = (t < SCAN_BLKS) ? bsum[t] : 0;
    sh[t] = v;
    __syncthreads();
    for (int off = 1; off < 256; off <<= 1) {
        int u = (t >= off) ? sh[t - off] : 0;
        __syncthreads();
        sh[t] += u;
        __syncthreads();
    }
    if (t < SCAN_BLKS) bsum[t] = sh[t] - v;  // exclusive
}

// stage 3: per-chunk LDS scan + block offset -> rp, cursor, rp[N]
__global__ __launch_bounds__(256) void k_scan3(const int* __restrict__ cnt, const int* __restrict__ bsum,
                                               int* __restrict__ rp, int* __restrict__ cursor) {
    __shared__ int sh[256];
    int t = threadIdx.x;
    int idx = blockIdx.x * 256 + t;
    int v = (idx < N_NODES) ? cnt[idx] : 0;
    sh[t] = v;
    __syncthreads();
    for (int off = 1; off < 256; off <<= 1) {
        int u = (t >= off) ? sh[t - off] : 0;
        __syncthreads();
        sh[t] += u;
        __syncthreads();
    }
    if (idx < N_NODES) {
        int excl = bsum[blockIdx.x] + sh[t] - v;
        rp[idx] = excl;
        cursor[idx] = excl;
        if (idx == N_NODES - 1) rp[N_NODES] = excl + v;
    }
}

__global__ void k_fill(const int* __restrict__ dst, int* __restrict__ cursor, int* __restrict__ eord) {
    int e = blockIdx.x * blockDim.x + threadIdx.x;
    if (e < N_EDGES) {
        int p = atomicAdd(&cursor[dst[e]], 1);
        eord[p] = e;
    }
}

// ---------- CSR-ordered edge tables (one-time random gather) ----------
// zo1[i,h] = a_s1[src,h] + a_e1[e,h]   (a_d and leaky applied later, per-dst)
__global__ void k_prep1(const int* __restrict__ eord, const int* __restrict__ src,
                        const float* __restrict__ as1, const float* __restrict__ ae1,
                        int* __restrict__ src_ord, float* __restrict__ zo1) {
    int i = blockIdx.x * blockDim.x + threadIdx.x;
    if (i >= N_EDGES) return;
    int e = eord[i];
    int s = src[e];
    src_ord[i] = s;
    zo1[i * 2 + 0] = as1[s * 2 + 0] + ae1[e * 2 + 0];
    zo1[i * 2 + 1] = as1[s * 2 + 1] + ae1[e * 2 + 1];
}

__global__ void k_prep2(const int* __restrict__ eord, const int* __restrict__ src_ord,
                        const float* __restrict__ as2, const float* __restrict__ ae2,
                        float* __restrict__ zo2) {
    int i = blockIdx.x * blockDim.x + threadIdx.x;
    if (i >= N_EDGES) return;
    zo2[i] = as2[src_ord[i]] + ae2[eord[i]];
}

// ---------- fused per-dst softmax + gather aggregation + bias + ELU ----------
// Block per dst node; streams CSR-ordered zo/src_ord. 3 passes (max, sum, aggregate).
template <int C, int H>
__global__ __launch_bounds__(C) void k_attn_gather(const int* __restrict__ rp, const int* __restrict__ src_ord,
                                                   const float* __restrict__ zo, const float* __restrict__ a_d,
                                                   const float* __restrict__ hfeat, const float* __restrict__ bias,
                                                   float* __restrict__ outp) {
    int n = blockIdx.x;
    int tid = threadIdx.x;
    int beg = rp[n], end = rp[n + 1];
    __shared__ int es[C];
    __shared__ float al[C * H];
    __shared__ float red[2 * H];
    float adn[H];
#pragma unroll
    for (int h = 0; h < H; ++h) adn[h] = a_d[n * H + h];

    // pass 1: segment max (contiguous zo stream)
    float mx[H];
#pragma unroll
    for (int h = 0; h < H; ++h) mx[h] = -3.4e38f;
    for (int i = beg + tid; i < end; i += C) {
#pragma unroll
        for (int h = 0; h < H; ++h) {
            float z = zo[i * H + h] + adn[h];
            z = z > 0.f ? z : NEG_SLOPE * z;
            mx[h] = fmaxf(mx[h], z);
        }
    }
#pragma unroll
    for (int h = 0; h < H; ++h) mx[h] = wmax64(mx[h]);
    if constexpr (C == 128) {
        if ((tid & 63) == 0) {
#pragma unroll
            for (int h = 0; h < H; ++h) red[(tid >> 6) * H + h] = mx[h];
        }
        __syncthreads();
#pragma unroll
        for (int h = 0; h < H; ++h) mx[h] = fmaxf(red[h], red[H + h]);
    }

    // pass 2: exp-sum
    float sm[H];
#pragma unroll
    for (int h = 0; h < H; ++h) sm[h] = 0.f;
    for (int i = beg + tid; i < end; i += C) {
#pragma unroll
        for (int h = 0; h < H; ++h) {
            float z = zo[i * H + h] + adn[h];
            z = z > 0.f ? z : NEG_SLOPE * z;
            sm[h] += __expf(z - mx[h]);
        }
    }
#pragma unroll
    for (int h = 0; h < H; ++h) sm[h] = wred64(sm[h]);
    if constexpr (C == 128) {
        __syncthreads();  // pass1 reads of red done
        if ((tid & 63) == 0) {
#pragma unroll
            for (int h = 0; h < H; ++h) red[(tid >> 6) * H + h] = sm[h];
        }
        __syncthreads();
#pragma unroll
        for (int h = 0; h < H; ++h) sm[h] = red[h] + red[H + h];
    }
    float dinv[H];
#pragma unroll
    for (int h = 0; h < H; ++h) dinv[h] = 1.f / (sm[h] + 1e-16f);

    // pass 3: staged weighted aggregation (src_ord/zo contiguous; hfeat rows random but coalesced)
    float acc = 0.f;
    const int hsel = (H == 2) ? (tid >> 6) : 0;
    for (int base = beg; base < end; base += C) {
        int cnt = min(C, end - base);
        __syncthreads();
        if (tid < cnt) {
            int i = base + tid;
            es[tid] = src_ord[i];
#pragma unroll
            for (int h = 0; h < H; ++h) {
                float z = zo[i * H + h] + adn[h];
                z = z > 0.f ? z : NEG_SLOPE * z;
                al[tid * H + h] = __expf(z - mx[h]) * dinv[h];
            }
        }
        __syncthreads();
#pragma unroll 4
        for (int i = 0; i < cnt; ++i) acc = fmaf(hfeat[(size_t)es[i] * C + tid], al[i * H + hsel], acc);
    }
    float v = acc + bias[tid];
    outp[(size_t)n * C + tid] = v > 0.f ? v : expm1f(v);
}

// ---------- classifier edge-side, CSR-grouped: warp per dst segment, ILP-2 ----------
__global__ __launch_bounds__(256) void k_final(const int* __restrict__ rp, const int* __restrict__ eord,
                                               const int* __restrict__ src_ord, const float* __restrict__ ea,
                                               const float* __restrict__ P1, const float* __restrict__ P2,
                                               const float* __restrict__ Wc1, const float* __restrict__ Wc2,
                                               const float* __restrict__ bc2, float* __restrict__ out) {
    __shared__ float wc1c[16 * 64];
    __shared__ float wc2s[64];
    int tid = threadIdx.x;
    for (int i = tid; i < 16 * 64; i += 256) wc1c[i] = Wc1[128 * 64 + i];
    if (tid < 64) wc2s[tid] = Wc2[tid];
    __syncthreads();
    int wid = tid >> 6, lane = tid & 63;
    int n = blockIdx.x * 4 + wid;
    if (n >= N_NODES) return;
    int beg = __builtin_amdgcn_readfirstlane(rp[n]);
    int end = __builtin_amdgcn_readfirstlane(rp[n + 1]);
    if (beg >= end) return;
    float p2 = P2[(size_t)n * 64 + lane];
    float bc = bc2[0];
    float w2 = wc2s[lane];
    int i = beg;
    for (; i + 1 < end; i += 2) {
        int e0 = __builtin_amdgcn_readfirstlane(eord[i]);
        int e1 = __builtin_amdgcn_readfirstlane(eord[i + 1]);
        int s0 = __builtin_amdgcn_readfirstlane(src_ord[i]);
        int s1 = __builtin_amdgcn_readfirstlane(src_ord[i + 1]);
        float h0 = p2 + P1[(size_t)s0 * 64 + lane];
        float h1 = p2 + P1[(size_t)s1 * 64 + lane];
        const float* ea0 = ea + (size_t)e0 * 16;
        const float* ea1 = ea + (size_t)e1 * 16;
#pragma unroll
        for (int k = 0; k < 16; ++k) {
            float wv = wc1c[k * 64 + lane];
            h0 = fmaf(ea0[k], wv, h0);
            h1 = fmaf(ea1[k], wv, h1);
        }
        h0 = fmaxf(h0, 0.f) * w2;
        h1 = fmaxf(h1, 0.f) * w2;
#pragma unroll
        for (int off = 32; off > 0; off >>= 1) {
            h0 += __shfl_xor(h0, off, 64);
            h1 += __shfl_xor(h1, off, 64);
        }
        if (lane == 0) {
            out[e0] = h0 + bc;
            out[e1] = h1 + bc;
        }
    }
    if (i < end) {
        int e0 = __builtin_amdgcn_readfirstlane(eord[i]);
        int s0 = __builtin_amdgcn_readfirstlane(src_ord[i]);
        float h0 = p2 + P1[(size_t)s0 * 64 + lane];
        const float* ea0 = ea + (size_t)e0 * 16;
#pragma unroll
        for (int k = 0; k < 16; ++k) h0 = fmaf(ea0[k], wc1c[k * 64 + lane], h0);
        h0 = fmaxf(h0, 0.f);
        float v = wred64(h0 * w2);
        if (lane == 0) out[e0] = v + bc;
    }
}

extern "C" void kernel_launch(void* const* d_in, const int* in_sizes, int n_in,
                              void* d_out, int out_size, void* d_ws, size_t ws_size,
                              hipStream_t stream) {
    const float* x     = (const float*)d_in[0];
    const int*   eidx  = (const int*)d_in[1];
    const float* ea    = (const float*)d_in[2];
    const float* W1    = (const float*)d_in[3];
    const float* atts1 = (const float*)d_in[4];
    const float* attd1 = (const float*)d_in[5];
    const float* We1   = (const float*)d_in[6];
    const float* atte1 = (const float*)d_in[7];
    const float* b1    = (const float*)d_in[8];
    const float* W2    = (const float*)d_in[9];
    const float* atts2 = (const float*)d_in[10];
    const float* attd2 = (const float*)d_in[11];
    const float* We2   = (const float*)d_in[12];
    const float* atte2 = (const float*)d_in[13];
    const float* b2    = (const float*)d_in[14];
    const float* Wc1   = (const float*)d_in[15];
    const float* bc1   = (const float*)d_in[16];
    const float* Wc2   = (const float*)d_in[17];
    const float* bc2   = (const float*)d_in[18];
    const int* srcp = eidx;
    const int* dstp = eidx + N_EDGES;
    float* out = (float*)d_out;

    char* w = (char*)d_ws;
    size_t off = 0;
    auto alloc = [&](size_t bytes) -> void* {
        void* p = w + off;
        off += (bytes + 255) & ~size_t(255);
        return p;
    };

    float* h1   = (float*)alloc(N_NODES * 128 * sizeof(float));  // conv1 features; later h2 / P1 / P2
    float* as1  = (float*)alloc(N_NODES * 2 * sizeof(float));
    float* ad1  = (float*)alloc(N_NODES * 2 * sizeof(float));
    float* ae1  = (float*)alloc(N_EDGES * 2 * sizeof(float));    // dead after k_prep1; reused as zo2
    float* ae2  = (float*)alloc(N_EDGES * sizeof(float));
    float* as2  = (float*)alloc(N_NODES * sizeof(float));
    float* ad2  = (float*)alloc(N_NODES * sizeof(float));
    float* ve1  = (float*)alloc(32 * sizeof(float));
    float* ve2  = (float*)alloc(16 * sizeof(float));
    int*   rp      = (int*)alloc((N_NODES + 1) * sizeof(int));
    int*   eord    = (int*)alloc(N_EDGES * sizeof(int));
    int*   cursor  = (int*)alloc(N_NODES * sizeof(int));
    int*   src_ord = (int*)alloc(N_EDGES * sizeof(int));
    float* zo1     = (float*)alloc(N_EDGES * 2 * sizeof(float));
    float* out1    = (float*)alloc(N_NODES * 128 * sizeof(float));
    float* out2    = (float*)alloc(N_NODES * 64 * sizeof(float));
    int*   bsum    = (int*)alloc(SCAN_BLKS * sizeof(int));

    // aliases (lifetime-disjoint)
    float* h2  = h1;              // [N,64]: gemm2 writes after h1's last read (gather1 pass3)
    float* P1  = h1;              // [N,64]: p12 writes after h2's last read (gather2 pass3)
    float* P2  = h1 + (size_t)N_NODES * 64;
    float* zo2 = ae1;             // [E]: prep2 writes after ae1's last read (prep1)

    // zeroed-every-call region
    char* zstart = w + off;
    int* cnt = (int*)alloc(N_NODES * sizeof(int));
    size_t zbytes = (size_t)((w + off) - zstart);
    hipMemsetAsync(zstart, 0, zbytes, stream);

    const int EB = (N_EDGES + 255) / 256;  // 3125

    // CSR build (shared by both conv layers + classifier)
    k_hist<<<EB, 256, 0, stream>>>(dstp, cnt);
    k_scan1<<<SCAN_BLKS, 256, 0, stream>>>(cnt, bsum);
    k_scan2<<<1, 256, 0, stream>>>(bsum);
    k_scan3<<<SCAN_BLKS, 256, 0, stream>>>(cnt, bsum, rp, cursor);
    k_fill<<<EB, 256, 0, stream>>>(dstp, cursor, eord);

    k_ve<<<1, 64, 0, stream>>>(We1, atte1, We2, atte2, ve1, ve2);
    k_gemm1<<<GRID1, 128, 0, stream>>>(x, W1, atts1, attd1, h1, as1, ad1);
    k_ae<<<EB, 256, 0, stream>>>(ea, ve1, ve2, ae1, ae2);

    // conv1: CSR-ordered tables, then fused softmax+aggregate+bias+ELU
    k_prep1<<<EB, 256, 0, stream>>>(eord, srcp, as1, ae1, src_ord, zo1);
    k_attn_gather<128, 2><<<N_NODES, 128, 0, stream>>>(rp, src_ord, zo1, ad1, h1, b1, out1);

    // conv2
    k_gemm2<<<GRID2, 64, 0, stream>>>(out1, W2, atts2, attd2, h2, as2, ad2);
    k_prep2<<<EB, 256, 0, stream>>>(eord, src_ord, as2, ae2, zo2);
    k_attn_gather<64, 1><<<N_NODES, 64, 0, stream>>>(rp, src_ord, zo2, ad2, h2, b2, out2);

    // edge classifier
    k_p12<<<GRID2, 64, 0, stream>>>(out2, Wc1, bc1, P1, P2);
    k_final<<<(N_NODES + 3) / 4, 256, 0, stream>>>(rp, eord, src_ord, ea, P1, P2, Wc1, Wc2, bc2, out);
}